// Round 1
// baseline (923.890 us; speedup 1.0000x reference)
//
#include <hip/hip_runtime.h>

#define N_NODES 100000
#define N_EDGES 1600000
#define IN_CH   256
#define HID     48
#define BN_EPS  1e-5f

// ---------- degree: one float atomic per edge ----------
__global__ void deg_kernel(const int* __restrict__ ei, float* __restrict__ deg) {
    int e = blockIdx.x * blockDim.x + threadIdx.x;
    if (e >= N_EDGES) return;
    int dst = ei[N_EDGES + e];
    if ((unsigned)dst < N_NODES) atomicAdd(&deg[dst], 1.0f);
}

// ---------- tiled f32 GEMM: out[M x 96] = in[M x K] @ [W0|W1]^T ----------
// W0, W1 are [48 x K] row-major. Block: 256 threads, 64 rows x 96 cols tile.
__global__ __launch_bounds__(256) void gemm96(const float* __restrict__ in, int M, int K,
                                              const float* __restrict__ W0,
                                              const float* __restrict__ W1,
                                              float* __restrict__ out) {
    __shared__ float xs[32][68];   // [kk][row], padded
    __shared__ float wsm[32][96];  // [kk][col]
    int tid = threadIdx.x;
    int n0  = blockIdx.x * 64;
    int ty  = tid >> 4, tx = tid & 15;   // each thread: rows ty*4..+3, cols tx*6..+5

    float acc[4][6];
#pragma unroll
    for (int i = 0; i < 4; i++)
#pragma unroll
        for (int c = 0; c < 6; c++) acc[i][c] = 0.f;

    for (int k0 = 0; k0 < K; k0 += 32) {
        // stage x tile (transposed to [kk][row])
#pragma unroll
        for (int l = 0; l < 2; l++) {
            int i  = tid + l * 256;        // 0..511
            int r  = i >> 3;
            int c4 = (i & 7) * 4;
            float4 v = make_float4(0.f, 0.f, 0.f, 0.f);
            if (n0 + r < M && k0 + c4 < K)
                v = *(const float4*)&in[(size_t)(n0 + r) * K + k0 + c4];
            xs[c4 + 0][r] = v.x; xs[c4 + 1][r] = v.y;
            xs[c4 + 2][r] = v.z; xs[c4 + 3][r] = v.w;
        }
        // stage W tile (transposed to [kk][col]); W is tiny, L1/L2 resident
        for (int i = tid; i < 32 * 96; i += 256) {
            int kk = i / 96, col = i % 96;
            const float* Wp = (col < 48) ? W0 : W1;
            int j = (col < 48) ? col : col - 48;
            wsm[kk][col] = (k0 + kk < K) ? Wp[(size_t)j * K + k0 + kk] : 0.f;
        }
        __syncthreads();
#pragma unroll
        for (int kk = 0; kk < 32; kk++) {
            float4 a = *(const float4*)&xs[kk][ty * 4];
            float b[6];
            *(float2*)&b[0] = *(const float2*)&wsm[kk][tx * 6 + 0];
            *(float2*)&b[2] = *(const float2*)&wsm[kk][tx * 6 + 2];
            *(float2*)&b[4] = *(const float2*)&wsm[kk][tx * 6 + 4];
            float av[4] = {a.x, a.y, a.z, a.w};
#pragma unroll
            for (int i = 0; i < 4; i++)
#pragma unroll
                for (int c = 0; c < 6; c++)
                    acc[i][c] = fmaf(av[i], b[c], acc[i][c]);
        }
        __syncthreads();
    }
#pragma unroll
    for (int i = 0; i < 4; i++) {
        int n = n0 + ty * 4 + i;
        if (n < M) {
#pragma unroll
            for (int c = 0; c < 6; c += 2) {
                float2 v = make_float2(acc[i][c], acc[i][c + 1]);
                *(float2*)&out[(size_t)n * 96 + tx * 6 + c] = v;
            }
        }
    }
}

// ---------- edge aggregation: 16 lanes per edge, 3 atomics each ----------
__global__ void agg_kernel(const int* __restrict__ ei, const float* __restrict__ P,
                           float* __restrict__ agg) {
    int t = blockIdx.x * blockDim.x + threadIdx.x;
    int e = t >> 4;
    int l = t & 15;
    if (e >= N_EDGES) return;
    int src = ei[e];
    int dst = ei[N_EDGES + e];
    if ((unsigned)src >= N_NODES || (unsigned)dst >= N_NODES) return;
    const float* p = &P[(size_t)src * 96];   // P part = cols 0..47 of PR
    float* a = &agg[(size_t)dst * 48];
    atomicAdd(&a[l +  0], p[l +  0]);
    atomicAdd(&a[l + 16], p[l + 16]);
    atomicAdd(&a[l + 32], p[l + 32]);
}

// ---------- mean + bias + BN(eval) + ReLU ----------
__global__ void post1_kernel(const float* __restrict__ agg, const float* __restrict__ deg,
                             const float* __restrict__ PR,
                             const float* __restrict__ b,  const float* __restrict__ g,
                             const float* __restrict__ be, const float* __restrict__ rm,
                             const float* __restrict__ rv, float* __restrict__ h) {
    int t = blockIdx.x * blockDim.x + threadIdx.x;
    if (t >= N_NODES * 48) return;
    int n = t / 48, j = t % 48;
    float mean = agg[t] / fmaxf(deg[n], 1.0f);
    float v = mean + b[j] + PR[(size_t)n * 96 + 48 + j];
    v = (v - rm[j]) * (g[j] * rsqrtf(rv[j] + BN_EPS)) + be[j];
    h[t] = fmaxf(v, 0.0f);
}

// ---------- layer-2 epilogue fused with 48->4 output matvec ----------
__global__ void out_kernel(const float* __restrict__ agg, const float* __restrict__ deg,
                           const float* __restrict__ PR,
                           const float* __restrict__ b2, const float* __restrict__ g2,
                           const float* __restrict__ be2, const float* __restrict__ rm2,
                           const float* __restrict__ rv2,
                           const float* __restrict__ wo, const float* __restrict__ bo,
                           float* __restrict__ out) {
    int t = blockIdx.x * blockDim.x + threadIdx.x;
    int node = t >> 4, l = t & 15;
    if (node >= N_NODES) return;
    float dg = fmaxf(deg[node], 1.0f);
    float p0 = 0.f, p1 = 0.f, p2 = 0.f, p3 = 0.f;
#pragma unroll
    for (int q = 0; q < 3; q++) {
        int j = l + q * 16;
        float v = agg[(size_t)node * 48 + j] / dg + b2[j] + PR[(size_t)node * 96 + 48 + j];
        v = (v - rm2[j]) * (g2[j] * rsqrtf(rv2[j] + BN_EPS)) + be2[j];
        v = fmaxf(v, 0.f);
        p0 = fmaf(v, wo[0 * 48 + j], p0);
        p1 = fmaf(v, wo[1 * 48 + j], p1);
        p2 = fmaf(v, wo[2 * 48 + j], p2);
        p3 = fmaf(v, wo[3 * 48 + j], p3);
    }
#pragma unroll
    for (int off = 8; off; off >>= 1) {
        p0 += __shfl_down(p0, off, 16);
        p1 += __shfl_down(p1, off, 16);
        p2 += __shfl_down(p2, off, 16);
        p3 += __shfl_down(p3, off, 16);
    }
    if (l == 0) {
        float4 o = make_float4(p0 + bo[0], p1 + bo[1], p2 + bo[2], p3 + bo[3]);
        *(float4*)&out[(size_t)node * 4] = o;
    }
}

extern "C" void kernel_launch(void* const* d_in, const int* in_sizes, int n_in,
                              void* d_out, int out_size, void* d_ws, size_t ws_size,
                              hipStream_t stream) {
    const float* x   = (const float*)d_in[0];
    const int*   ei  = (const int*)d_in[1];
    const float* w1l = (const float*)d_in[2];
    const float* b1  = (const float*)d_in[3];
    const float* w1r = (const float*)d_in[4];
    const float* g1  = (const float*)d_in[5];
    const float* be1 = (const float*)d_in[6];
    const float* rm1 = (const float*)d_in[7];
    const float* rv1 = (const float*)d_in[8];
    const float* w2l = (const float*)d_in[9];
    const float* b2  = (const float*)d_in[10];
    const float* w2r = (const float*)d_in[11];
    const float* g2  = (const float*)d_in[12];
    const float* be2 = (const float*)d_in[13];
    const float* rm2 = (const float*)d_in[14];
    const float* rv2 = (const float*)d_in[15];
    const float* wo  = (const float*)d_in[16];
    const float* bo  = (const float*)d_in[17];
    float* out = (float*)d_out;

    float* ws  = (float*)d_ws;
    float* PR  = ws;                                  // N*96
    float* AGG = ws + (size_t)N_NODES * 96;           // N*48
    float* H1  = AGG + (size_t)N_NODES * 48;          // N*48
    float* DEG = H1 + (size_t)N_NODES * 48;           // N
    // total: N*193*4 bytes = 77.2 MB

    hipMemsetAsync(DEG, 0, N_NODES * sizeof(float), stream);
    hipMemsetAsync(AGG, 0, (size_t)N_NODES * 48 * sizeof(float), stream);
    deg_kernel<<<(N_EDGES + 255) / 256, 256, 0, stream>>>(ei, DEG);

    // layer 1: project first (aggregation commutes with linear), then aggregate 48-dim
    gemm96<<<(N_NODES + 63) / 64, 256, 0, stream>>>(x, N_NODES, IN_CH, w1l, w1r, PR);
    agg_kernel<<<(N_EDGES * 16) / 256, 256, 0, stream>>>(ei, PR, AGG);
    post1_kernel<<<(N_NODES * 48 + 255) / 256, 256, 0, stream>>>(AGG, DEG, PR,
                                                                 b1, g1, be1, rm1, rv1, H1);

    // layer 2
    gemm96<<<(N_NODES + 63) / 64, 256, 0, stream>>>(H1, N_NODES, HID, w2l, w2r, PR);
    hipMemsetAsync(AGG, 0, (size_t)N_NODES * 48 * sizeof(float), stream);
    agg_kernel<<<(N_EDGES * 16) / 256, 256, 0, stream>>>(ei, PR, AGG);
    out_kernel<<<(N_NODES * 16 + 255) / 256, 256, 0, stream>>>(AGG, DEG, PR,
                                                               b2, g2, be2, rm2, rv2,
                                                               wo, bo, out);
}

// Round 2
// 648.816 us; speedup vs baseline: 1.4240x; 1.4240x over previous
//
#include <hip/hip_runtime.h>

#define N_NODES 100000
#define N_EDGES 1600000
#define IN_CH   256
#define HID     48
#define BN_EPS  1e-5f
#define SCAN_NB ((N_NODES + 1023) / 1024)   // 98

// ---------- CSR build: histogram of dst ----------
__global__ void hist_kernel(const int* __restrict__ ei, int* __restrict__ cnt) {
    int e = blockIdx.x * blockDim.x + threadIdx.x;
    if (e >= N_EDGES) return;
    int dst = ei[N_EDGES + e];
    if ((unsigned)dst < N_NODES) atomicAdd(&cnt[dst], 1);
}

// ---------- scan k1: per-block (1024-elem chunk) sums ----------
__global__ __launch_bounds__(256) void scan_k1(const int* __restrict__ cnt, int* __restrict__ bsum) {
    __shared__ int lds[256];
    int b = blockIdx.x, t = threadIdx.x;
    int i0 = b * 1024 + t * 4;
    int s = 0;
#pragma unroll
    for (int j = 0; j < 4; j++) { int i = i0 + j; if (i < N_NODES) s += cnt[i]; }
    lds[t] = s; __syncthreads();
    for (int o = 128; o; o >>= 1) { if (t < o) lds[t] += lds[t + o]; __syncthreads(); }
    if (t == 0) bsum[b] = lds[0];
}

// ---------- scan k2: exclusive scan of block sums (single block) ----------
__global__ void scan_k2(const int* __restrict__ bsum, int* __restrict__ bex, int nb) {
    __shared__ int lds[128];
    int t = threadIdx.x;
    int v = (t < nb) ? bsum[t] : 0;
    lds[t] = v; __syncthreads();
    for (int o = 1; o < 128; o <<= 1) {
        int u = (t >= o) ? lds[t - o] : 0;
        __syncthreads();
        lds[t] += u;
        __syncthreads();
    }
    if (t < nb) bex[t] = lds[t] - v;
}

// ---------- scan k3: full exclusive offsets, write off[] and cursor[] ----------
__global__ __launch_bounds__(256) void scan_k3(const int* __restrict__ cnt, const int* __restrict__ bex,
                                               int* __restrict__ off, int* __restrict__ cur) {
    __shared__ int lds[256];
    int b = blockIdx.x, t = threadIdx.x;
    int i0 = b * 1024 + t * 4;
    int c[4]; int s = 0;
#pragma unroll
    for (int j = 0; j < 4; j++) { int i = i0 + j; c[j] = (i < N_NODES) ? cnt[i] : 0; s += c[j]; }
    lds[t] = s; __syncthreads();
    for (int o = 1; o < 256; o <<= 1) {
        int u = (t >= o) ? lds[t - o] : 0;
        __syncthreads();
        lds[t] += u;
        __syncthreads();
    }
    int ex = lds[t] - s + bex[b];
#pragma unroll
    for (int j = 0; j < 4; j++) {
        int i = i0 + j;
        if (i < N_NODES) { off[i] = ex; cur[i] = ex; ex += c[j]; }
    }
}

// ---------- scatter src into CSR slots ----------
__global__ void scatter_kernel(const int* __restrict__ ei, int* __restrict__ cur,
                               int* __restrict__ csr) {
    int e = blockIdx.x * blockDim.x + threadIdx.x;
    if (e >= N_EDGES) return;
    int src = ei[e];
    int dst = ei[N_EDGES + e];
    if ((unsigned)src >= N_NODES || (unsigned)dst >= N_NODES) return;
    int pos = atomicAdd(&cur[dst], 1);
    csr[pos] = src;
}

// ---------- tiled f32 GEMM: out[M x 96] = in[M x K] @ [W0|W1]^T ----------
__global__ __launch_bounds__(256) void gemm96(const float* __restrict__ in, int M, int K,
                                              const float* __restrict__ W0,
                                              const float* __restrict__ W1,
                                              float* __restrict__ out) {
    __shared__ float xs[32][68];   // [kk][row], padded
    __shared__ float wsm[32][96];  // [kk][col]
    int tid = threadIdx.x;
    int n0  = blockIdx.x * 64;
    int ty  = tid >> 4, tx = tid & 15;

    float acc[4][6];
#pragma unroll
    for (int i = 0; i < 4; i++)
#pragma unroll
        for (int c = 0; c < 6; c++) acc[i][c] = 0.f;

    for (int k0 = 0; k0 < K; k0 += 32) {
#pragma unroll
        for (int l = 0; l < 2; l++) {
            int i  = tid + l * 256;
            int r  = i >> 3;
            int c4 = (i & 7) * 4;
            float4 v = make_float4(0.f, 0.f, 0.f, 0.f);
            if (n0 + r < M && k0 + c4 < K)
                v = *(const float4*)&in[(size_t)(n0 + r) * K + k0 + c4];
            xs[c4 + 0][r] = v.x; xs[c4 + 1][r] = v.y;
            xs[c4 + 2][r] = v.z; xs[c4 + 3][r] = v.w;
        }
        for (int i = tid; i < 32 * 96; i += 256) {
            int kk = i / 96, col = i % 96;
            const float* Wp = (col < 48) ? W0 : W1;
            int j = (col < 48) ? col : col - 48;
            wsm[kk][col] = (k0 + kk < K) ? Wp[(size_t)j * K + k0 + kk] : 0.f;
        }
        __syncthreads();
#pragma unroll
        for (int kk = 0; kk < 32; kk++) {
            float4 a = *(const float4*)&xs[kk][ty * 4];
            float b[6];
            *(float2*)&b[0] = *(const float2*)&wsm[kk][tx * 6 + 0];
            *(float2*)&b[2] = *(const float2*)&wsm[kk][tx * 6 + 2];
            *(float2*)&b[4] = *(const float2*)&wsm[kk][tx * 6 + 4];
            float av[4] = {a.x, a.y, a.z, a.w};
#pragma unroll
            for (int i = 0; i < 4; i++)
#pragma unroll
                for (int c = 0; c < 6; c++)
                    acc[i][c] = fmaf(av[i], b[c], acc[i][c]);
        }
        __syncthreads();
    }
#pragma unroll
    for (int i = 0; i < 4; i++) {
        int n = n0 + ty * 4 + i;
        if (n < M) {
#pragma unroll
            for (int c = 0; c < 6; c += 2) {
                float2 v = make_float2(acc[i][c], acc[i][c + 1]);
                *(float2*)&out[(size_t)n * 96 + tx * 6 + c] = v;
            }
        }
    }
}

// ---------- CSR gather-reduce aggregation: 16 lanes per node ----------
__global__ __launch_bounds__(256) void agg_csr(const int* __restrict__ off, const int* __restrict__ cnt,
                                               const int* __restrict__ csr, const float* __restrict__ P,
                                               float* __restrict__ agg) {
    int t = blockIdx.x * blockDim.x + threadIdx.x;
    int node = t >> 4, l = t & 15;
    if (node >= N_NODES) return;
    int s = off[node], len = cnt[node];
    float a0 = 0.f, a1 = 0.f, a2 = 0.f;
    int i = 0;
    for (; i + 4 <= len; i += 4) {
        int s0 = csr[s + i], s1 = csr[s + i + 1], s2 = csr[s + i + 2], s3 = csr[s + i + 3];
        const float* p0 = P + (size_t)s0 * 96;
        const float* p1 = P + (size_t)s1 * 96;
        const float* p2 = P + (size_t)s2 * 96;
        const float* p3 = P + (size_t)s3 * 96;
        a0 += p0[l]; a1 += p0[l + 16]; a2 += p0[l + 32];
        a0 += p1[l]; a1 += p1[l + 16]; a2 += p1[l + 32];
        a0 += p2[l]; a1 += p2[l + 16]; a2 += p2[l + 32];
        a0 += p3[l]; a1 += p3[l + 16]; a2 += p3[l + 32];
    }
    for (; i < len; i++) {
        const float* p = P + (size_t)csr[s + i] * 96;
        a0 += p[l]; a1 += p[l + 16]; a2 += p[l + 32];
    }
    float* a = &agg[(size_t)node * 48];
    a[l] = a0; a[l + 16] = a1; a[l + 32] = a2;
}

// ---------- mean + bias + BN(eval) + ReLU ----------
__global__ void post1_kernel(const float* __restrict__ agg, const int* __restrict__ cnt,
                             const float* __restrict__ PR,
                             const float* __restrict__ b,  const float* __restrict__ g,
                             const float* __restrict__ be, const float* __restrict__ rm,
                             const float* __restrict__ rv, float* __restrict__ h) {
    int t = blockIdx.x * blockDim.x + threadIdx.x;
    if (t >= N_NODES * 48) return;
    int n = t / 48, j = t % 48;
    float mean = agg[t] / fmaxf((float)cnt[n], 1.0f);
    float v = mean + b[j] + PR[(size_t)n * 96 + 48 + j];
    v = (v - rm[j]) * (g[j] * rsqrtf(rv[j] + BN_EPS)) + be[j];
    h[t] = fmaxf(v, 0.0f);
}

// ---------- layer-2 epilogue fused with 48->4 output matvec ----------
__global__ void out_kernel(const float* __restrict__ agg, const int* __restrict__ cnt,
                           const float* __restrict__ PR,
                           const float* __restrict__ b2, const float* __restrict__ g2,
                           const float* __restrict__ be2, const float* __restrict__ rm2,
                           const float* __restrict__ rv2,
                           const float* __restrict__ wo, const float* __restrict__ bo,
                           float* __restrict__ out) {
    int t = blockIdx.x * blockDim.x + threadIdx.x;
    int node = t >> 4, l = t & 15;
    if (node >= N_NODES) return;
    float dg = fmaxf((float)cnt[node], 1.0f);
    float p0 = 0.f, p1 = 0.f, p2 = 0.f, p3 = 0.f;
#pragma unroll
    for (int q = 0; q < 3; q++) {
        int j = l + q * 16;
        float v = agg[(size_t)node * 48 + j] / dg + b2[j] + PR[(size_t)node * 96 + 48 + j];
        v = (v - rm2[j]) * (g2[j] * rsqrtf(rv2[j] + BN_EPS)) + be2[j];
        v = fmaxf(v, 0.f);
        p0 = fmaf(v, wo[0 * 48 + j], p0);
        p1 = fmaf(v, wo[1 * 48 + j], p1);
        p2 = fmaf(v, wo[2 * 48 + j], p2);
        p3 = fmaf(v, wo[3 * 48 + j], p3);
    }
#pragma unroll
    for (int offm = 8; offm; offm >>= 1) {
        p0 += __shfl_down(p0, offm, 16);
        p1 += __shfl_down(p1, offm, 16);
        p2 += __shfl_down(p2, offm, 16);
        p3 += __shfl_down(p3, offm, 16);
    }
    if (l == 0) {
        float4 o = make_float4(p0 + bo[0], p1 + bo[1], p2 + bo[2], p3 + bo[3]);
        *(float4*)&out[(size_t)node * 4] = o;
    }
}

extern "C" void kernel_launch(void* const* d_in, const int* in_sizes, int n_in,
                              void* d_out, int out_size, void* d_ws, size_t ws_size,
                              hipStream_t stream) {
    const float* x   = (const float*)d_in[0];
    const int*   ei  = (const int*)d_in[1];
    const float* w1l = (const float*)d_in[2];
    const float* b1  = (const float*)d_in[3];
    const float* w1r = (const float*)d_in[4];
    const float* g1  = (const float*)d_in[5];
    const float* be1 = (const float*)d_in[6];
    const float* rm1 = (const float*)d_in[7];
    const float* rv1 = (const float*)d_in[8];
    const float* w2l = (const float*)d_in[9];
    const float* b2  = (const float*)d_in[10];
    const float* w2r = (const float*)d_in[11];
    const float* g2  = (const float*)d_in[12];
    const float* be2 = (const float*)d_in[13];
    const float* rm2 = (const float*)d_in[14];
    const float* rv2 = (const float*)d_in[15];
    const float* wo  = (const float*)d_in[16];
    const float* bo  = (const float*)d_in[17];
    float* out = (float*)d_out;

    float* ws  = (float*)d_ws;
    float* PR  = ws;                                  // N*96 f32
    float* AGG = PR + (size_t)N_NODES * 96;           // N*48 f32
    float* H1  = AGG + (size_t)N_NODES * 48;          // N*48 f32
    int*   CNT = (int*)(H1 + (size_t)N_NODES * 48);   // N
    int*   OFF = CNT + N_NODES;                       // N
    int*   CUR = OFF + N_NODES;                       // N
    int*   BSUM = CUR + N_NODES;                      // 128
    int*   BEX  = BSUM + 128;                         // 128
    int*   CSR  = BEX + 128;                          // E
    // total ≈ 84.4 MB

    // ---- CSR build (once; graph shared by both layers) ----
    hipMemsetAsync(CNT, 0, N_NODES * sizeof(int), stream);
    hist_kernel<<<(N_EDGES + 255) / 256, 256, 0, stream>>>(ei, CNT);
    scan_k1<<<SCAN_NB, 256, 0, stream>>>(CNT, BSUM);
    scan_k2<<<1, 128, 0, stream>>>(BSUM, BEX, SCAN_NB);
    scan_k3<<<SCAN_NB, 256, 0, stream>>>(CNT, BEX, OFF, CUR);
    scatter_kernel<<<(N_EDGES + 255) / 256, 256, 0, stream>>>(ei, CUR, CSR);

    // ---- layer 1: project first, then aggregate 48-dim ----
    gemm96<<<(N_NODES + 63) / 64, 256, 0, stream>>>(x, N_NODES, IN_CH, w1l, w1r, PR);
    agg_csr<<<(N_NODES * 16 + 255) / 256, 256, 0, stream>>>(OFF, CNT, CSR, PR, AGG);
    post1_kernel<<<(N_NODES * 48 + 255) / 256, 256, 0, stream>>>(AGG, CNT, PR,
                                                                 b1, g1, be1, rm1, rv1, H1);

    // ---- layer 2 ----
    gemm96<<<(N_NODES + 63) / 64, 256, 0, stream>>>(H1, N_NODES, HID, w2l, w2r, PR);
    agg_csr<<<(N_NODES * 16 + 255) / 256, 256, 0, stream>>>(OFF, CNT, CSR, PR, AGG);
    out_kernel<<<(N_NODES * 16 + 255) / 256, 256, 0, stream>>>(AGG, CNT, PR,
                                                               b2, g2, be2, rm2, rv2,
                                                               wo, bo, out);
}

// Round 5
// 516.462 us; speedup vs baseline: 1.7889x; 1.2563x over previous
//
#include <hip/hip_runtime.h>
#include <hip/hip_bf16.h>

#define N_NODES 100000
#define N_EDGES 1600000
#define IN_CH   256
#define BN_EPS  1e-5f
#define SCAN_NB 98

typedef __attribute__((ext_vector_type(8))) short bf16x8;
typedef __attribute__((ext_vector_type(4))) float f32x4;
typedef __attribute__((ext_vector_type(4))) int   i32x4;

// f32 -> bf16 round-to-nearest-even, on raw bits (trivially copyable types only)
__device__ inline unsigned f2bf(float x) {
    unsigned u = __float_as_uint(x);
    return (u + 0x7fffu + ((u >> 16) & 1u)) >> 16;
}
__device__ inline unsigned pk2(float x, float y) {
    return f2bf(x) | (f2bf(y) << 16);
}
__device__ inline bf16x8 pack8(float4 a, float4 b) {
    i32x4 r;
    r.x = (int)pk2(a.x, a.y); r.y = (int)pk2(a.z, a.w);
    r.z = (int)pk2(b.x, b.y); r.w = (int)pk2(b.z, b.w);
    return __builtin_bit_cast(bf16x8, r);
}
__device__ inline float lo16(unsigned u) { return __uint_as_float(u << 16); }
__device__ inline float hi16(unsigned u) { return __uint_as_float(u & 0xffff0000u); }

// ---------- CSR build ----------
__global__ void hist_kernel(const int* __restrict__ ei, int* __restrict__ cnt) {
    int e = blockIdx.x * blockDim.x + threadIdx.x;
    if (e >= N_EDGES) return;
    int dst = ei[N_EDGES + e];
    if ((unsigned)dst < N_NODES) atomicAdd(&cnt[dst], 1);
}

__global__ __launch_bounds__(256) void scan_k1(const int* __restrict__ cnt, int* __restrict__ bsum) {
    __shared__ int lds[256];
    int b = blockIdx.x, t = threadIdx.x;
    int i0 = b * 1024 + t * 4;
    int s = 0;
#pragma unroll
    for (int j = 0; j < 4; j++) { int i = i0 + j; if (i < N_NODES) s += cnt[i]; }
    lds[t] = s; __syncthreads();
    for (int o = 128; o; o >>= 1) { if (t < o) lds[t] += lds[t + o]; __syncthreads(); }
    if (t == 0) bsum[b] = lds[0];
}

__global__ void scan_k2(const int* __restrict__ bsum, int* __restrict__ bex, int nb) {
    __shared__ int lds[128];
    int t = threadIdx.x;
    int v = (t < nb) ? bsum[t] : 0;
    lds[t] = v; __syncthreads();
    for (int o = 1; o < 128; o <<= 1) {
        int u = (t >= o) ? lds[t - o] : 0;
        __syncthreads();
        lds[t] += u;
        __syncthreads();
    }
    if (t < nb) bex[t] = lds[t] - v;
}

__global__ __launch_bounds__(256) void scan_k3(const int* __restrict__ cnt, const int* __restrict__ bex,
                                               int* __restrict__ off, int* __restrict__ cur) {
    __shared__ int lds[256];
    int b = blockIdx.x, t = threadIdx.x;
    int i0 = b * 1024 + t * 4;
    int c[4]; int s = 0;
#pragma unroll
    for (int j = 0; j < 4; j++) { int i = i0 + j; c[j] = (i < N_NODES) ? cnt[i] : 0; s += c[j]; }
    lds[t] = s; __syncthreads();
    for (int o = 1; o < 256; o <<= 1) {
        int u = (t >= o) ? lds[t - o] : 0;
        __syncthreads();
        lds[t] += u;
        __syncthreads();
    }
    int ex = lds[t] - s + bex[b];
#pragma unroll
    for (int j = 0; j < 4; j++) {
        int i = i0 + j;
        if (i < N_NODES) { off[i] = ex; cur[i] = ex; ex += c[j]; }
    }
}

__global__ void scatter_kernel(const int* __restrict__ ei, int* __restrict__ cur,
                               int* __restrict__ csr) {
    int e = blockIdx.x * blockDim.x + threadIdx.x;
    if (e >= N_EDGES) return;
    int src = ei[e];
    int dst = ei[N_EDGES + e];
    if ((unsigned)src >= N_NODES || (unsigned)dst >= N_NODES) return;
    int pos = atomicAdd(&cur[dst], 1);
    csr[pos] = src;
}

// ---------- MFMA GEMM, layer 1: in f32 [M][256] -> P bf16 [M][48], R f32 [M][48] ----------
// Block: 128 rows, 4 waves; wave w owns M-tiles {2w, 2w+1}. Cols 96 = 6 tiles of 16.
// Fragment mapping (m89/m92/m97-verified family): A row=lane&15, k=k0+8*(lane>>4)+j (contig);
// B col=lane&15, same k; C/D col=lane&15, row=(lane>>4)*4+reg.
__global__ __launch_bounds__(256) void gemm1_mfma(const float* __restrict__ in,
        const float* __restrict__ W0, const float* __restrict__ W1,
        __hip_bfloat16* __restrict__ P, float* __restrict__ R) {
    __shared__ bf16x8 wlds[8 * 6 * 64];   // 48 KiB, fragment-major: [kstep][tile][lane]
    int tid = threadIdx.x;
    for (int s = tid; s < 8 * 6 * 64; s += 256) {
        int lane = s & 63, tile = (s >> 6) % 6, kstep = s / 384;
        int c = tile * 16 + (lane & 15);
        int k0 = kstep * 32 + (lane >> 4) * 8;
        const float* Wp = (c < 48) ? &W0[(size_t)c * IN_CH] : &W1[(size_t)(c - 48) * IN_CH];
        float4 a = *(const float4*)&Wp[k0];
        float4 b = *(const float4*)&Wp[k0 + 4];
        wlds[s] = pack8(a, b);
    }
    __syncthreads();

    int w = tid >> 6, lane = tid & 63;
    int lr = lane & 15, kq = lane >> 4;
    int rbase = blockIdx.x * 128 + w * 32;
    f32x4 acc[2][6] = {};

    for (int kstep = 0; kstep < 8; kstep++) {
        int kb = kstep * 32 + kq * 8;
        bf16x8 afr[2] = {};
#pragma unroll
        for (int mt = 0; mt < 2; mt++) {
            int row = rbase + mt * 16 + lr;
            if (row < N_NODES) {
                const float* ip = &in[(size_t)row * IN_CH + kb];
                afr[mt] = pack8(*(const float4*)ip, *(const float4*)(ip + 4));
            }
        }
        bf16x8 bfr[6];
#pragma unroll
        for (int t = 0; t < 6; t++) bfr[t] = wlds[(kstep * 6 + t) * 64 + lane];
#pragma unroll
        for (int t = 0; t < 6; t++)
#pragma unroll
            for (int mt = 0; mt < 2; mt++)
                acc[mt][t] = __builtin_amdgcn_mfma_f32_16x16x32_bf16(afr[mt], bfr[t], acc[mt][t], 0, 0, 0);
    }
#pragma unroll
    for (int mt = 0; mt < 2; mt++)
#pragma unroll
        for (int t = 0; t < 6; t++)
#pragma unroll
            for (int j = 0; j < 4; j++) {
                int row = rbase + mt * 16 + kq * 4 + j;
                if (row < N_NODES) {
                    float v = acc[mt][t][j];
                    int col = t * 16 + lr;
                    if (t < 3) P[(size_t)row * 48 + col] = __float2bfloat16(v);
                    else       R[(size_t)row * 48 + (col - 48)] = v;
                }
            }
}

// ---------- MFMA GEMM, layer 2: in bf16 [M][64] (zero-padded K) -> P bf16, R f32 ----------
__global__ __launch_bounds__(256) void gemm2_mfma(const __hip_bfloat16* __restrict__ inb,
        const float* __restrict__ W0, const float* __restrict__ W1,
        __hip_bfloat16* __restrict__ P, float* __restrict__ R) {
    __shared__ bf16x8 wlds[2 * 6 * 64];   // 12 KiB
    int tid = threadIdx.x;
    for (int s = tid; s < 2 * 6 * 64; s += 256) {
        int lane = s & 63, tile = (s >> 6) % 6, kstep = s / 384;
        int c = tile * 16 + (lane & 15);
        int k0 = kstep * 32 + (lane >> 4) * 8;
        const float* Wp = (c < 48) ? &W0[(size_t)c * 48] : &W1[(size_t)(c - 48) * 48];
        float v[8];
#pragma unroll
        for (int j = 0; j < 8; j++) { int k = k0 + j; v[j] = (k < 48) ? Wp[k] : 0.f; }
        wlds[s] = pack8(make_float4(v[0], v[1], v[2], v[3]), make_float4(v[4], v[5], v[6], v[7]));
    }
    __syncthreads();

    int w = tid >> 6, lane = tid & 63;
    int lr = lane & 15, kq = lane >> 4;
    int rbase = blockIdx.x * 128 + w * 32;
    f32x4 acc[2][6] = {};

    for (int kstep = 0; kstep < 2; kstep++) {
        int kb = kstep * 32 + kq * 8;
        bf16x8 afr[2] = {};
#pragma unroll
        for (int mt = 0; mt < 2; mt++) {
            int row = rbase + mt * 16 + lr;
            if (row < N_NODES)
                afr[mt] = *(const bf16x8*)&inb[(size_t)row * 64 + kb];
        }
        bf16x8 bfr[6];
#pragma unroll
        for (int t = 0; t < 6; t++) bfr[t] = wlds[(kstep * 6 + t) * 64 + lane];
#pragma unroll
        for (int t = 0; t < 6; t++)
#pragma unroll
            for (int mt = 0; mt < 2; mt++)
                acc[mt][t] = __builtin_amdgcn_mfma_f32_16x16x32_bf16(afr[mt], bfr[t], acc[mt][t], 0, 0, 0);
    }
#pragma unroll
    for (int mt = 0; mt < 2; mt++)
#pragma unroll
        for (int t = 0; t < 6; t++)
#pragma unroll
            for (int j = 0; j < 4; j++) {
                int row = rbase + mt * 16 + kq * 4 + j;
                if (row < N_NODES) {
                    float v = acc[mt][t][j];
                    int col = t * 16 + lr;
                    if (t < 3) P[(size_t)row * 48 + col] = __float2bfloat16(v);
                    else       R[(size_t)row * 48 + (col - 48)] = v;
                }
            }
}

// ---------- CSR gather-reduce over bf16 P: 8 lanes per node, dword (bf16x2) loads ----------
__global__ __launch_bounds__(256) void agg_csr_b16(const int* __restrict__ off, const int* __restrict__ cnt,
                                                   const int* __restrict__ csr,
                                                   const unsigned* __restrict__ P32,  // [N][24] dwords
                                                   float* __restrict__ agg) {
    int t = blockIdx.x * blockDim.x + threadIdx.x;
    int node = t >> 3, l = t & 7;
    if (node >= N_NODES) return;
    int s = off[node], len = cnt[node];
    float a0 = 0.f, a1 = 0.f, a2 = 0.f, a3 = 0.f, a4 = 0.f, a5 = 0.f;
    int i = 0;
    for (; i + 4 <= len; i += 4) {
        int sx[4];
#pragma unroll
        for (int q = 0; q < 4; q++) sx[q] = csr[s + i + q];
        unsigned uu[4][3];
#pragma unroll
        for (int q = 0; q < 4; q++) {
            const unsigned* p = P32 + (size_t)sx[q] * 24 + l;
            uu[q][0] = p[0]; uu[q][1] = p[8]; uu[q][2] = p[16];
        }
#pragma unroll
        for (int q = 0; q < 4; q++) {
            a0 += lo16(uu[q][0]); a1 += hi16(uu[q][0]);
            a2 += lo16(uu[q][1]); a3 += hi16(uu[q][1]);
            a4 += lo16(uu[q][2]); a5 += hi16(uu[q][2]);
        }
    }
    for (; i < len; i++) {
        const unsigned* p = P32 + (size_t)csr[s + i] * 24 + l;
        unsigned u0 = p[0], u1 = p[8], u2 = p[16];
        a0 += lo16(u0); a1 += hi16(u0);
        a2 += lo16(u1); a3 += hi16(u1);
        a4 += lo16(u2); a5 += hi16(u2);
    }
    size_t base = (size_t)node * 48;
    *(float2*)&agg[base +  0 + 2 * l] = make_float2(a0, a1);
    *(float2*)&agg[base + 16 + 2 * l] = make_float2(a2, a3);
    *(float2*)&agg[base + 32 + 2 * l] = make_float2(a4, a5);
}

// ---------- mean + bias + BN(eval) + ReLU -> H1 bf16 [N][64] (pad pre-zeroed) ----------
__global__ void post1_kernel(const float* __restrict__ agg, const int* __restrict__ cnt,
                             const float* __restrict__ R,
                             const float* __restrict__ b,  const float* __restrict__ g,
                             const float* __restrict__ be, const float* __restrict__ rm,
                             const float* __restrict__ rv, __hip_bfloat16* __restrict__ h) {
    int t = blockIdx.x * blockDim.x + threadIdx.x;
    if (t >= N_NODES * 48) return;
    int n = t / 48, j = t % 48;
    float mean = agg[t] / fmaxf((float)cnt[n], 1.0f);
    float v = mean + b[j] + R[t];
    v = (v - rm[j]) * (g[j] * rsqrtf(rv[j] + BN_EPS)) + be[j];
    h[(size_t)n * 64 + j] = __float2bfloat16(fmaxf(v, 0.0f));
}

// ---------- layer-2 epilogue fused with 48->4 output matvec ----------
__global__ void out_kernel(const float* __restrict__ agg, const int* __restrict__ cnt,
                           const float* __restrict__ R,
                           const float* __restrict__ b2, const float* __restrict__ g2,
                           const float* __restrict__ be2, const float* __restrict__ rm2,
                           const float* __restrict__ rv2,
                           const float* __restrict__ wo, const float* __restrict__ bo,
                           float* __restrict__ out) {
    int t = blockIdx.x * blockDim.x + threadIdx.x;
    int node = t >> 4, l = t & 15;
    if (node >= N_NODES) return;
    float dg = fmaxf((float)cnt[node], 1.0f);
    float p0 = 0.f, p1 = 0.f, p2 = 0.f, p3 = 0.f;
#pragma unroll
    for (int q = 0; q < 3; q++) {
        int j = l + q * 16;
        float v = agg[(size_t)node * 48 + j] / dg + b2[j] + R[(size_t)node * 48 + j];
        v = (v - rm2[j]) * (g2[j] * rsqrtf(rv2[j] + BN_EPS)) + be2[j];
        v = fmaxf(v, 0.f);
        p0 = fmaf(v, wo[0 * 48 + j], p0);
        p1 = fmaf(v, wo[1 * 48 + j], p1);
        p2 = fmaf(v, wo[2 * 48 + j], p2);
        p3 = fmaf(v, wo[3 * 48 + j], p3);
    }
#pragma unroll
    for (int offm = 8; offm; offm >>= 1) {
        p0 += __shfl_down(p0, offm, 16);
        p1 += __shfl_down(p1, offm, 16);
        p2 += __shfl_down(p2, offm, 16);
        p3 += __shfl_down(p3, offm, 16);
    }
    if (l == 0) {
        float4 o = make_float4(p0 + bo[0], p1 + bo[1], p2 + bo[2], p3 + bo[3]);
        *(float4*)&out[(size_t)node * 4] = o;
    }
}

extern "C" void kernel_launch(void* const* d_in, const int* in_sizes, int n_in,
                              void* d_out, int out_size, void* d_ws, size_t ws_size,
                              hipStream_t stream) {
    const float* x   = (const float*)d_in[0];
    const int*   ei  = (const int*)d_in[1];
    const float* w1l = (const float*)d_in[2];
    const float* b1  = (const float*)d_in[3];
    const float* w1r = (const float*)d_in[4];
    const float* g1  = (const float*)d_in[5];
    const float* be1 = (const float*)d_in[6];
    const float* rm1 = (const float*)d_in[7];
    const float* rv1 = (const float*)d_in[8];
    const float* w2l = (const float*)d_in[9];
    const float* b2  = (const float*)d_in[10];
    const float* w2r = (const float*)d_in[11];
    const float* g2  = (const float*)d_in[12];
    const float* be2 = (const float*)d_in[13];
    const float* rm2 = (const float*)d_in[14];
    const float* rv2 = (const float*)d_in[15];
    const float* wo  = (const float*)d_in[16];
    const float* bo  = (const float*)d_in[17];
    float* out = (float*)d_out;

    // workspace layout (all 16B-aligned)
    char* w = (char*)d_ws;
    float*           Rbuf = (float*)w;                       w += (size_t)N_NODES * 48 * 4;  // 19.2 MB
    float*           AGG  = (float*)w;                       w += (size_t)N_NODES * 48 * 4;  // 19.2 MB
    __hip_bfloat16*  P    = (__hip_bfloat16*)w;              w += (size_t)N_NODES * 48 * 2;  //  9.6 MB
    __hip_bfloat16*  H1   = (__hip_bfloat16*)w;              w += (size_t)N_NODES * 64 * 2;  // 12.8 MB
    int*             CNT  = (int*)w;                         w += (size_t)N_NODES * 4;
    int*             OFF  = (int*)w;                         w += (size_t)N_NODES * 4;
    int*             CUR  = (int*)w;                         w += (size_t)N_NODES * 4;
    int*             BSUM = (int*)w;                         w += 128 * 4;
    int*             BEX  = (int*)w;                         w += 128 * 4;
    int*             CSR  = (int*)w;                         // E * 4 = 6.4 MB
    // total ≈ 68.3 MB

    (void)hipMemsetAsync(CNT, 0, N_NODES * sizeof(int), stream);
    (void)hipMemsetAsync(H1, 0, (size_t)N_NODES * 64 * 2, stream);   // zero K-pad

    // CSR build (shared by both layers)
    hist_kernel<<<(N_EDGES + 255) / 256, 256, 0, stream>>>(ei, CNT);
    scan_k1<<<SCAN_NB, 256, 0, stream>>>(CNT, BSUM);
    scan_k2<<<1, 128, 0, stream>>>(BSUM, BEX, SCAN_NB);
    scan_k3<<<SCAN_NB, 256, 0, stream>>>(CNT, BEX, OFF, CUR);
    scatter_kernel<<<(N_EDGES + 255) / 256, 256, 0, stream>>>(ei, CUR, CSR);

    // layer 1
    gemm1_mfma<<<(N_NODES + 127) / 128, 256, 0, stream>>>(x, w1l, w1r, P, Rbuf);
    agg_csr_b16<<<(N_NODES * 8 + 255) / 256, 256, 0, stream>>>(OFF, CNT, CSR, (const unsigned*)P, AGG);
    post1_kernel<<<(N_NODES * 48 + 255) / 256, 256, 0, stream>>>(AGG, CNT, Rbuf,
                                                                 b1, g1, be1, rm1, rv1, H1);

    // layer 2
    gemm2_mfma<<<(N_NODES + 127) / 128, 256, 0, stream>>>(H1, w2l, w2r, P, Rbuf);
    agg_csr_b16<<<(N_NODES * 8 + 255) / 256, 256, 0, stream>>>(OFF, CNT, CSR, (const unsigned*)P, AGG);
    out_kernel<<<(N_NODES * 16 + 255) / 256, 256, 0, stream>>>(AGG, CNT, Rbuf,
                                                               b2, g2, be2, rm2, rv2,
                                                               wo, bo, out);
}

// Round 6
// 483.115 us; speedup vs baseline: 1.9124x; 1.0690x over previous
//
#include <hip/hip_runtime.h>
#include <hip/hip_bf16.h>

#define N_NODES 100000
#define N_EDGES 1600000
#define IN_CH   256
#define BN_EPS  1e-5f
#define SCAN_NB 98
#define NPART   8
#define PART_SZ 12500           // N_NODES / NPART exactly
#define NGRP    128             // blocks per partition; grid = NPART*NGRP = 1024

typedef __attribute__((ext_vector_type(8))) short bf16x8;
typedef __attribute__((ext_vector_type(4))) float f32x4;
typedef __attribute__((ext_vector_type(4))) int   i32x4;

// f32 -> bf16 round-to-nearest-even, on raw bits (trivially copyable types only)
__device__ inline unsigned f2bf(float x) {
    unsigned u = __float_as_uint(x);
    return (u + 0x7fffu + ((u >> 16) & 1u)) >> 16;
}
__device__ inline unsigned pk2(float x, float y) {
    return f2bf(x) | (f2bf(y) << 16);
}
__device__ inline bf16x8 pack8(float4 a, float4 b) {
    i32x4 r;
    r.x = (int)pk2(a.x, a.y); r.y = (int)pk2(a.z, a.w);
    r.z = (int)pk2(b.x, b.y); r.w = (int)pk2(b.z, b.w);
    return __builtin_bit_cast(bf16x8, r);
}
__device__ inline float lo16(unsigned u) { return __uint_as_float(u << 16); }
__device__ inline float hi16(unsigned u) { return __uint_as_float(u & 0xffff0000u); }

// ---------- CSR build, XCD-partitioned ----------
// Block b owns dst-partition p = b&7; with round-robin block->XCD dispatch all
// writers of cnt/cur/csr region p sit on one XCD -> L2-local atomics & writes.
__global__ __launch_bounds__(256) void hist_part(const int* __restrict__ ei, int* __restrict__ cnt) {
    int p = blockIdx.x & (NPART - 1);
    int g = blockIdx.x >> 3;
    int lo = p * PART_SZ, hi = lo + PART_SZ;
    for (int e = g * 256 + (int)threadIdx.x; e < N_EDGES; e += NGRP * 256) {
        int dst = ei[N_EDGES + e];
        if (dst >= lo && dst < hi) atomicAdd(&cnt[dst], 1);
    }
}

__global__ __launch_bounds__(256) void scatter_part(const int* __restrict__ ei, int* __restrict__ cur,
                                                    int* __restrict__ csr) {
    int p = blockIdx.x & (NPART - 1);
    int g = blockIdx.x >> 3;
    int lo = p * PART_SZ, hi = lo + PART_SZ;
    for (int e = g * 256 + (int)threadIdx.x; e < N_EDGES; e += NGRP * 256) {
        int dst = ei[N_EDGES + e];
        if (dst >= lo && dst < hi) {
            int src = ei[e];
            if ((unsigned)src < N_NODES) {
                int pos = atomicAdd(&cur[dst], 1);
                csr[pos] = src;
            }
        }
    }
}

__global__ __launch_bounds__(256) void scan_k1(const int* __restrict__ cnt, int* __restrict__ bsum) {
    __shared__ int lds[256];
    int b = blockIdx.x, t = threadIdx.x;
    int i0 = b * 1024 + t * 4;
    int s = 0;
#pragma unroll
    for (int j = 0; j < 4; j++) { int i = i0 + j; if (i < N_NODES) s += cnt[i]; }
    lds[t] = s; __syncthreads();
    for (int o = 128; o; o >>= 1) { if (t < o) lds[t] += lds[t + o]; __syncthreads(); }
    if (t == 0) bsum[b] = lds[0];
}

__global__ void scan_k2(const int* __restrict__ bsum, int* __restrict__ bex, int nb) {
    __shared__ int lds[128];
    int t = threadIdx.x;
    int v = (t < nb) ? bsum[t] : 0;
    lds[t] = v; __syncthreads();
    for (int o = 1; o < 128; o <<= 1) {
        int u = (t >= o) ? lds[t - o] : 0;
        __syncthreads();
        lds[t] += u;
        __syncthreads();
    }
    if (t < nb) bex[t] = lds[t] - v;
}

__global__ __launch_bounds__(256) void scan_k3(const int* __restrict__ cnt, const int* __restrict__ bex,
                                               int* __restrict__ off, int* __restrict__ cur) {
    __shared__ int lds[256];
    int b = blockIdx.x, t = threadIdx.x;
    int i0 = b * 1024 + t * 4;
    int c[4]; int s = 0;
#pragma unroll
    for (int j = 0; j < 4; j++) { int i = i0 + j; c[j] = (i < N_NODES) ? cnt[i] : 0; s += c[j]; }
    lds[t] = s; __syncthreads();
    for (int o = 1; o < 256; o <<= 1) {
        int u = (t >= o) ? lds[t - o] : 0;
        __syncthreads();
        lds[t] += u;
        __syncthreads();
    }
    int ex = lds[t] - s + bex[b];
#pragma unroll
    for (int j = 0; j < 4; j++) {
        int i = i0 + j;
        if (i < N_NODES) { off[i] = ex; cur[i] = ex; ex += c[j]; }
    }
}

// ---------- MFMA GEMM, layer 1: in f32 [M][256] -> P bf16 [M][48], R f32 [M][48] ----------
__global__ __launch_bounds__(256) void gemm1_mfma(const float* __restrict__ in,
        const float* __restrict__ W0, const float* __restrict__ W1,
        __hip_bfloat16* __restrict__ P, float* __restrict__ R) {
    __shared__ bf16x8 wlds[8 * 6 * 64];   // 48 KiB, fragment-major: [kstep][tile][lane]
    int tid = threadIdx.x;
    for (int s = tid; s < 8 * 6 * 64; s += 256) {
        int lane = s & 63, tile = (s >> 6) % 6, kstep = s / 384;
        int c = tile * 16 + (lane & 15);
        int k0 = kstep * 32 + (lane >> 4) * 8;
        const float* Wp = (c < 48) ? &W0[(size_t)c * IN_CH] : &W1[(size_t)(c - 48) * IN_CH];
        float4 a = *(const float4*)&Wp[k0];
        float4 b = *(const float4*)&Wp[k0 + 4];
        wlds[s] = pack8(a, b);
    }
    __syncthreads();

    int w = tid >> 6, lane = tid & 63;
    int lr = lane & 15, kq = lane >> 4;
    int rbase = blockIdx.x * 128 + w * 32;
    f32x4 acc[2][6] = {};

    for (int kstep = 0; kstep < 8; kstep++) {
        int kb = kstep * 32 + kq * 8;
        bf16x8 afr[2] = {};
#pragma unroll
        for (int mt = 0; mt < 2; mt++) {
            int row = rbase + mt * 16 + lr;
            if (row < N_NODES) {
                const float* ip = &in[(size_t)row * IN_CH + kb];
                afr[mt] = pack8(*(const float4*)ip, *(const float4*)(ip + 4));
            }
        }
        bf16x8 bfr[6];
#pragma unroll
        for (int t = 0; t < 6; t++) bfr[t] = wlds[(kstep * 6 + t) * 64 + lane];
#pragma unroll
        for (int t = 0; t < 6; t++)
#pragma unroll
            for (int mt = 0; mt < 2; mt++)
                acc[mt][t] = __builtin_amdgcn_mfma_f32_16x16x32_bf16(afr[mt], bfr[t], acc[mt][t], 0, 0, 0);
    }
#pragma unroll
    for (int mt = 0; mt < 2; mt++)
#pragma unroll
        for (int t = 0; t < 6; t++)
#pragma unroll
            for (int j = 0; j < 4; j++) {
                int row = rbase + mt * 16 + kq * 4 + j;
                if (row < N_NODES) {
                    float v = acc[mt][t][j];
                    int col = t * 16 + lr;
                    if (t < 3) P[(size_t)row * 48 + col] = __float2bfloat16(v);
                    else       R[(size_t)row * 48 + (col - 48)] = v;
                }
            }
}

// ---------- MFMA GEMM, layer 2: in bf16 [M][64] (zero-padded K) -> P bf16, R f32 ----------
__global__ __launch_bounds__(256) void gemm2_mfma(const __hip_bfloat16* __restrict__ inb,
        const float* __restrict__ W0, const float* __restrict__ W1,
        __hip_bfloat16* __restrict__ P, float* __restrict__ R) {
    __shared__ bf16x8 wlds[2 * 6 * 64];   // 12 KiB
    int tid = threadIdx.x;
    for (int s = tid; s < 2 * 6 * 64; s += 256) {
        int lane = s & 63, tile = (s >> 6) % 6, kstep = s / 384;
        int c = tile * 16 + (lane & 15);
        int k0 = kstep * 32 + (lane >> 4) * 8;
        const float* Wp = (c < 48) ? &W0[(size_t)c * 48] : &W1[(size_t)(c - 48) * 48];
        float v[8];
#pragma unroll
        for (int j = 0; j < 8; j++) { int k = k0 + j; v[j] = (k < 48) ? Wp[k] : 0.f; }
        wlds[s] = pack8(make_float4(v[0], v[1], v[2], v[3]), make_float4(v[4], v[5], v[6], v[7]));
    }
    __syncthreads();

    int w = tid >> 6, lane = tid & 63;
    int lr = lane & 15, kq = lane >> 4;
    int rbase = blockIdx.x * 128 + w * 32;
    f32x4 acc[2][6] = {};

    for (int kstep = 0; kstep < 2; kstep++) {
        int kb = kstep * 32 + kq * 8;
        bf16x8 afr[2] = {};
#pragma unroll
        for (int mt = 0; mt < 2; mt++) {
            int row = rbase + mt * 16 + lr;
            if (row < N_NODES)
                afr[mt] = *(const bf16x8*)&inb[(size_t)row * 64 + kb];
        }
        bf16x8 bfr[6];
#pragma unroll
        for (int t = 0; t < 6; t++) bfr[t] = wlds[(kstep * 6 + t) * 64 + lane];
#pragma unroll
        for (int t = 0; t < 6; t++)
#pragma unroll
            for (int mt = 0; mt < 2; mt++)
                acc[mt][t] = __builtin_amdgcn_mfma_f32_16x16x32_bf16(afr[mt], bfr[t], acc[mt][t], 0, 0, 0);
    }
#pragma unroll
    for (int mt = 0; mt < 2; mt++)
#pragma unroll
        for (int t = 0; t < 6; t++)
#pragma unroll
            for (int j = 0; j < 4; j++) {
                int row = rbase + mt * 16 + kq * 4 + j;
                if (row < N_NODES) {
                    float v = acc[mt][t][j];
                    int col = t * 16 + lr;
                    if (t < 3) P[(size_t)row * 48 + col] = __float2bfloat16(v);
                    else       R[(size_t)row * 48 + (col - 48)] = v;
                }
            }
}

// ---------- CSR gather-reduce over bf16 P: 8 lanes per node, dword (bf16x2) loads ----------
__global__ __launch_bounds__(256) void agg_csr_b16(const int* __restrict__ off, const int* __restrict__ cnt,
                                                   const int* __restrict__ csr,
                                                   const unsigned* __restrict__ P32,  // [N][24] dwords
                                                   float* __restrict__ agg) {
    int t = blockIdx.x * blockDim.x + threadIdx.x;
    int node = t >> 3, l = t & 7;
    if (node >= N_NODES) return;
    int s = off[node], len = cnt[node];
    float a0 = 0.f, a1 = 0.f, a2 = 0.f, a3 = 0.f, a4 = 0.f, a5 = 0.f;
    int i = 0;
    for (; i + 4 <= len; i += 4) {
        int sx[4];
#pragma unroll
        for (int q = 0; q < 4; q++) sx[q] = csr[s + i + q];
        unsigned uu[4][3];
#pragma unroll
        for (int q = 0; q < 4; q++) {
            const unsigned* p = P32 + (size_t)sx[q] * 24 + l;
            uu[q][0] = p[0]; uu[q][1] = p[8]; uu[q][2] = p[16];
        }
#pragma unroll
        for (int q = 0; q < 4; q++) {
            a0 += lo16(uu[q][0]); a1 += hi16(uu[q][0]);
            a2 += lo16(uu[q][1]); a3 += hi16(uu[q][1]);
            a4 += lo16(uu[q][2]); a5 += hi16(uu[q][2]);
        }
    }
    for (; i < len; i++) {
        const unsigned* p = P32 + (size_t)csr[s + i] * 24 + l;
        unsigned u0 = p[0], u1 = p[8], u2 = p[16];
        a0 += lo16(u0); a1 += hi16(u0);
        a2 += lo16(u1); a3 += hi16(u1);
        a4 += lo16(u2); a5 += hi16(u2);
    }
    size_t base = (size_t)node * 48;
    *(float2*)&agg[base +  0 + 2 * l] = make_float2(a0, a1);
    *(float2*)&agg[base + 16 + 2 * l] = make_float2(a2, a3);
    *(float2*)&agg[base + 32 + 2 * l] = make_float2(a4, a5);
}

// ---------- mean + bias + BN(eval) + ReLU -> H1 bf16 [N][64] (pad pre-zeroed) ----------
__global__ void post1_kernel(const float* __restrict__ agg, const int* __restrict__ cnt,
                             const float* __restrict__ R,
                             const float* __restrict__ b,  const float* __restrict__ g,
                             const float* __restrict__ be, const float* __restrict__ rm,
                             const float* __restrict__ rv, __hip_bfloat16* __restrict__ h) {
    int t = blockIdx.x * blockDim.x + threadIdx.x;
    if (t >= N_NODES * 48) return;
    int n = t / 48, j = t % 48;
    float mean = agg[t] / fmaxf((float)cnt[n], 1.0f);
    float v = mean + b[j] + R[t];
    v = (v - rm[j]) * (g[j] * rsqrtf(rv[j] + BN_EPS)) + be[j];
    h[(size_t)n * 64 + j] = __float2bfloat16(fmaxf(v, 0.0f));
}

// ---------- layer-2 epilogue fused with 48->4 output matvec ----------
__global__ void out_kernel(const float* __restrict__ agg, const int* __restrict__ cnt,
                           const float* __restrict__ R,
                           const float* __restrict__ b2, const float* __restrict__ g2,
                           const float* __restrict__ be2, const float* __restrict__ rm2,
                           const float* __restrict__ rv2,
                           const float* __restrict__ wo, const float* __restrict__ bo,
                           float* __restrict__ out) {
    int t = blockIdx.x * blockDim.x + threadIdx.x;
    int node = t >> 4, l = t & 15;
    if (node >= N_NODES) return;
    float dg = fmaxf((float)cnt[node], 1.0f);
    float p0 = 0.f, p1 = 0.f, p2 = 0.f, p3 = 0.f;
#pragma unroll
    for (int q = 0; q < 3; q++) {
        int j = l + q * 16;
        float v = agg[(size_t)node * 48 + j] / dg + b2[j] + R[(size_t)node * 48 + j];
        v = (v - rm2[j]) * (g2[j] * rsqrtf(rv2[j] + BN_EPS)) + be2[j];
        v = fmaxf(v, 0.f);
        p0 = fmaf(v, wo[0 * 48 + j], p0);
        p1 = fmaf(v, wo[1 * 48 + j], p1);
        p2 = fmaf(v, wo[2 * 48 + j], p2);
        p3 = fmaf(v, wo[3 * 48 + j], p3);
    }
#pragma unroll
    for (int offm = 8; offm; offm >>= 1) {
        p0 += __shfl_down(p0, offm, 16);
        p1 += __shfl_down(p1, offm, 16);
        p2 += __shfl_down(p2, offm, 16);
        p3 += __shfl_down(p3, offm, 16);
    }
    if (l == 0) {
        float4 o = make_float4(p0 + bo[0], p1 + bo[1], p2 + bo[2], p3 + bo[3]);
        *(float4*)&out[(size_t)node * 4] = o;
    }
}

extern "C" void kernel_launch(void* const* d_in, const int* in_sizes, int n_in,
                              void* d_out, int out_size, void* d_ws, size_t ws_size,
                              hipStream_t stream) {
    const float* x   = (const float*)d_in[0];
    const int*   ei  = (const int*)d_in[1];
    const float* w1l = (const float*)d_in[2];
    const float* b1  = (const float*)d_in[3];
    const float* w1r = (const float*)d_in[4];
    const float* g1  = (const float*)d_in[5];
    const float* be1 = (const float*)d_in[6];
    const float* rm1 = (const float*)d_in[7];
    const float* rv1 = (const float*)d_in[8];
    const float* w2l = (const float*)d_in[9];
    const float* b2  = (const float*)d_in[10];
    const float* w2r = (const float*)d_in[11];
    const float* g2  = (const float*)d_in[12];
    const float* be2 = (const float*)d_in[13];
    const float* rm2 = (const float*)d_in[14];
    const float* rv2 = (const float*)d_in[15];
    const float* wo  = (const float*)d_in[16];
    const float* bo  = (const float*)d_in[17];
    float* out = (float*)d_out;

    // workspace layout (all 16B-aligned)
    char* w = (char*)d_ws;
    float*           Rbuf = (float*)w;                       w += (size_t)N_NODES * 48 * 4;  // 19.2 MB
    float*           AGG  = (float*)w;                       w += (size_t)N_NODES * 48 * 4;  // 19.2 MB
    __hip_bfloat16*  P    = (__hip_bfloat16*)w;              w += (size_t)N_NODES * 48 * 2;  //  9.6 MB
    __hip_bfloat16*  H1   = (__hip_bfloat16*)w;              w += (size_t)N_NODES * 64 * 2;  // 12.8 MB
    int*             CNT  = (int*)w;                         w += (size_t)N_NODES * 4;
    int*             OFF  = (int*)w;                         w += (size_t)N_NODES * 4;
    int*             CUR  = (int*)w;                         w += (size_t)N_NODES * 4;
    int*             BSUM = (int*)w;                         w += 128 * 4;
    int*             BEX  = (int*)w;                         w += 128 * 4;
    int*             CSR  = (int*)w;                         // E * 4 = 6.4 MB
    // total ≈ 68.3 MB

    (void)hipMemsetAsync(CNT, 0, N_NODES * sizeof(int), stream);
    (void)hipMemsetAsync(H1, 0, (size_t)N_NODES * 64 * 2, stream);   // zero K-pad

    // CSR build (shared by both layers), XCD-partitioned
    hist_part<<<NPART * NGRP, 256, 0, stream>>>(ei, CNT);
    scan_k1<<<SCAN_NB, 256, 0, stream>>>(CNT, BSUM);
    scan_k2<<<1, 128, 0, stream>>>(BSUM, BEX, SCAN_NB);
    scan_k3<<<SCAN_NB, 256, 0, stream>>>(CNT, BEX, OFF, CUR);
    scatter_part<<<NPART * NGRP, 256, 0, stream>>>(ei, CUR, CSR);

    // layer 1
    gemm1_mfma<<<(N_NODES + 127) / 128, 256, 0, stream>>>(x, w1l, w1r, P, Rbuf);
    agg_csr_b16<<<(N_NODES * 8 + 255) / 256, 256, 0, stream>>>(OFF, CNT, CSR, (const unsigned*)P, AGG);
    post1_kernel<<<(N_NODES * 48 + 255) / 256, 256, 0, stream>>>(AGG, CNT, Rbuf,
                                                                 b1, g1, be1, rm1, rv1, H1);

    // layer 2
    gemm2_mfma<<<(N_NODES + 127) / 128, 256, 0, stream>>>(H1, w2l, w2r, P, Rbuf);
    agg_csr_b16<<<(N_NODES * 8 + 255) / 256, 256, 0, stream>>>(OFF, CNT, CSR, (const unsigned*)P, AGG);
    out_kernel<<<(N_NODES * 16 + 255) / 256, 256, 0, stream>>>(AGG, CNT, Rbuf,
                                                               b2, g2, be2, rm2, rv2,
                                                               wo, bo, out);
}

// Round 7
// 476.565 us; speedup vs baseline: 1.9386x; 1.0137x over previous
//
#include <hip/hip_runtime.h>
#include <hip/hip_bf16.h>

#define N_NODES 100000
#define N_EDGES 1600000
#define IN_CH   256
#define BN_EPS  1e-5f
#define SCAN_NB 98
#define NPART   8
#define PART_SZ 12500           // N_NODES / NPART exactly
#define NGRP    800             // groups per partition; NGRP*256*8 = 1.6384M >= E

typedef __attribute__((ext_vector_type(8))) short bf16x8;
typedef __attribute__((ext_vector_type(4))) float f32x4;
typedef __attribute__((ext_vector_type(4))) int   i32x4;

// f32 -> bf16 round-to-nearest-even, on raw bits (trivially copyable types only)
__device__ inline unsigned f2bf(float x) {
    unsigned u = __float_as_uint(x);
    return (u + 0x7fffu + ((u >> 16) & 1u)) >> 16;
}
__device__ inline unsigned pk2(float x, float y) {
    return f2bf(x) | (f2bf(y) << 16);
}
__device__ inline bf16x8 pack8(float4 a, float4 b) {
    i32x4 r;
    r.x = (int)pk2(a.x, a.y); r.y = (int)pk2(a.z, a.w);
    r.z = (int)pk2(b.x, b.y); r.w = (int)pk2(b.z, b.w);
    return __builtin_bit_cast(bf16x8, r);
}
__device__ inline float lo16(unsigned u) { return __uint_as_float(u << 16); }
__device__ inline float hi16(unsigned u) { return __uint_as_float(u & 0xffff0000u); }

// ---------- CSR build, XCD-partitioned + 8-edge ILP ----------
// Block b owns dst-partition p = b&7 (round-robin block->XCD dispatch => all
// writers of cnt/cur/csr region p sit on one XCD). Each thread handles 8
// contiguous edges via two 16B non-temporal vector loads -> 8 independent
// match/atomic ops in flight (kernel was latency-bound at 4% VALUBusy).
__global__ __launch_bounds__(256) void hist_part(const int* __restrict__ ei, int* __restrict__ cnt) {
    int p = blockIdx.x & (NPART - 1);
    int g = blockIdx.x >> 3;
    int lo = p * PART_SZ, hi = lo + PART_SZ;
    int e0 = (g * 256 + (int)threadIdx.x) * 8;
    if (e0 >= N_EDGES) return;
    const i32x4* dp = (const i32x4*)(ei + N_EDGES + e0);
    i32x4 d0 = __builtin_nontemporal_load(dp);
    i32x4 d1 = __builtin_nontemporal_load(dp + 1);
    int d[8] = {d0.x, d0.y, d0.z, d0.w, d1.x, d1.y, d1.z, d1.w};
#pragma unroll
    for (int j = 0; j < 8; j++)
        if (d[j] >= lo && d[j] < hi) atomicAdd(&cnt[d[j]], 1);
}

__global__ __launch_bounds__(256) void scatter_part(const int* __restrict__ ei, int* __restrict__ cur,
                                                    int* __restrict__ csr) {
    int p = blockIdx.x & (NPART - 1);
    int g = blockIdx.x >> 3;
    int lo = p * PART_SZ, hi = lo + PART_SZ;
    int e0 = (g * 256 + (int)threadIdx.x) * 8;
    if (e0 >= N_EDGES) return;
    const i32x4* dp = (const i32x4*)(ei + N_EDGES + e0);
    const i32x4* sp = (const i32x4*)(ei + e0);
    i32x4 d0 = __builtin_nontemporal_load(dp);
    i32x4 d1 = __builtin_nontemporal_load(dp + 1);
    i32x4 s0 = __builtin_nontemporal_load(sp);
    i32x4 s1 = __builtin_nontemporal_load(sp + 1);
    int d[8] = {d0.x, d0.y, d0.z, d0.w, d1.x, d1.y, d1.z, d1.w};
    int s[8] = {s0.x, s0.y, s0.z, s0.w, s1.x, s1.y, s1.z, s1.w};
#pragma unroll
    for (int j = 0; j < 8; j++) {
        if (d[j] >= lo && d[j] < hi && (unsigned)s[j] < N_NODES) {
            int pos = atomicAdd(&cur[d[j]], 1);
            csr[pos] = s[j];
        }
    }
}

__global__ __launch_bounds__(256) void scan_k1(const int* __restrict__ cnt, int* __restrict__ bsum) {
    __shared__ int lds[256];
    int b = blockIdx.x, t = threadIdx.x;
    int i0 = b * 1024 + t * 4;
    int s = 0;
#pragma unroll
    for (int j = 0; j < 4; j++) { int i = i0 + j; if (i < N_NODES) s += cnt[i]; }
    lds[t] = s; __syncthreads();
    for (int o = 128; o; o >>= 1) { if (t < o) lds[t] += lds[t + o]; __syncthreads(); }
    if (t == 0) bsum[b] = lds[0];
}

__global__ void scan_k2(const int* __restrict__ bsum, int* __restrict__ bex, int nb) {
    __shared__ int lds[128];
    int t = threadIdx.x;
    int v = (t < nb) ? bsum[t] : 0;
    lds[t] = v; __syncthreads();
    for (int o = 1; o < 128; o <<= 1) {
        int u = (t >= o) ? lds[t - o] : 0;
        __syncthreads();
        lds[t] += u;
        __syncthreads();
    }
    if (t < nb) bex[t] = lds[t] - v;
}

__global__ __launch_bounds__(256) void scan_k3(const int* __restrict__ cnt, const int* __restrict__ bex,
                                               int* __restrict__ off, int* __restrict__ cur) {
    __shared__ int lds[256];
    int b = blockIdx.x, t = threadIdx.x;
    int i0 = b * 1024 + t * 4;
    int c[4]; int s = 0;
#pragma unroll
    for (int j = 0; j < 4; j++) { int i = i0 + j; c[j] = (i < N_NODES) ? cnt[i] : 0; s += c[j]; }
    lds[t] = s; __syncthreads();
    for (int o = 1; o < 256; o <<= 1) {
        int u = (t >= o) ? lds[t - o] : 0;
        __syncthreads();
        lds[t] += u;
        __syncthreads();
    }
    int ex = lds[t] - s + bex[b];
#pragma unroll
    for (int j = 0; j < 4; j++) {
        int i = i0 + j;
        if (i < N_NODES) { off[i] = ex; cur[i] = ex; ex += c[j]; }
    }
}

// ---------- MFMA GEMM, layer 1: in f32 [M][256] -> P bf16 [M][48], R f32 [M][48] ----------
__global__ __launch_bounds__(256) void gemm1_mfma(const float* __restrict__ in,
        const float* __restrict__ W0, const float* __restrict__ W1,
        __hip_bfloat16* __restrict__ P, float* __restrict__ R) {
    __shared__ bf16x8 wlds[8 * 6 * 64];   // 48 KiB, fragment-major: [kstep][tile][lane]
    int tid = threadIdx.x;
    for (int s = tid; s < 8 * 6 * 64; s += 256) {
        int lane = s & 63, tile = (s >> 6) % 6, kstep = s / 384;
        int c = tile * 16 + (lane & 15);
        int k0 = kstep * 32 + (lane >> 4) * 8;
        const float* Wp = (c < 48) ? &W0[(size_t)c * IN_CH] : &W1[(size_t)(c - 48) * IN_CH];
        float4 a = *(const float4*)&Wp[k0];
        float4 b = *(const float4*)&Wp[k0 + 4];
        wlds[s] = pack8(a, b);
    }
    __syncthreads();

    int w = tid >> 6, lane = tid & 63;
    int lr = lane & 15, kq = lane >> 4;
    int rbase = blockIdx.x * 128 + w * 32;
    f32x4 acc[2][6] = {};

    for (int kstep = 0; kstep < 8; kstep++) {
        int kb = kstep * 32 + kq * 8;
        bf16x8 afr[2] = {};
#pragma unroll
        for (int mt = 0; mt < 2; mt++) {
            int row = rbase + mt * 16 + lr;
            if (row < N_NODES) {
                const float* ip = &in[(size_t)row * IN_CH + kb];
                afr[mt] = pack8(*(const float4*)ip, *(const float4*)(ip + 4));
            }
        }
        bf16x8 bfr[6];
#pragma unroll
        for (int t = 0; t < 6; t++) bfr[t] = wlds[(kstep * 6 + t) * 64 + lane];
#pragma unroll
        for (int t = 0; t < 6; t++)
#pragma unroll
            for (int mt = 0; mt < 2; mt++)
                acc[mt][t] = __builtin_amdgcn_mfma_f32_16x16x32_bf16(afr[mt], bfr[t], acc[mt][t], 0, 0, 0);
    }
#pragma unroll
    for (int mt = 0; mt < 2; mt++)
#pragma unroll
        for (int t = 0; t < 6; t++)
#pragma unroll
            for (int j = 0; j < 4; j++) {
                int row = rbase + mt * 16 + kq * 4 + j;
                if (row < N_NODES) {
                    float v = acc[mt][t][j];
                    int col = t * 16 + lr;
                    if (t < 3) P[(size_t)row * 48 + col] = __float2bfloat16(v);
                    else       R[(size_t)row * 48 + (col - 48)] = v;
                }
            }
}

// ---------- MFMA GEMM, layer 2: in bf16 [M][64] (zero-padded K) -> P bf16, R f32 ----------
__global__ __launch_bounds__(256) void gemm2_mfma(const __hip_bfloat16* __restrict__ inb,
        const float* __restrict__ W0, const float* __restrict__ W1,
        __hip_bfloat16* __restrict__ P, float* __restrict__ R) {
    __shared__ bf16x8 wlds[2 * 6 * 64];   // 12 KiB
    int tid = threadIdx.x;
    for (int s = tid; s < 2 * 6 * 64; s += 256) {
        int lane = s & 63, tile = (s >> 6) % 6, kstep = s / 384;
        int c = tile * 16 + (lane & 15);
        int k0 = kstep * 32 + (lane >> 4) * 8;
        const float* Wp = (c < 48) ? &W0[(size_t)c * 48] : &W1[(size_t)(c - 48) * 48];
        float v[8];
#pragma unroll
        for (int j = 0; j < 8; j++) { int k = k0 + j; v[j] = (k < 48) ? Wp[k] : 0.f; }
        wlds[s] = pack8(make_float4(v[0], v[1], v[2], v[3]), make_float4(v[4], v[5], v[6], v[7]));
    }
    __syncthreads();

    int w = tid >> 6, lane = tid & 63;
    int lr = lane & 15, kq = lane >> 4;
    int rbase = blockIdx.x * 128 + w * 32;
    f32x4 acc[2][6] = {};

    for (int kstep = 0; kstep < 2; kstep++) {
        int kb = kstep * 32 + kq * 8;
        bf16x8 afr[2] = {};
#pragma unroll
        for (int mt = 0; mt < 2; mt++) {
            int row = rbase + mt * 16 + lr;
            if (row < N_NODES)
                afr[mt] = *(const bf16x8*)&inb[(size_t)row * 64 + kb];
        }
        bf16x8 bfr[6];
#pragma unroll
        for (int t = 0; t < 6; t++) bfr[t] = wlds[(kstep * 6 + t) * 64 + lane];
#pragma unroll
        for (int t = 0; t < 6; t++)
#pragma unroll
            for (int mt = 0; mt < 2; mt++)
                acc[mt][t] = __builtin_amdgcn_mfma_f32_16x16x32_bf16(afr[mt], bfr[t], acc[mt][t], 0, 0, 0);
    }
#pragma unroll
    for (int mt = 0; mt < 2; mt++)
#pragma unroll
        for (int t = 0; t < 6; t++)
#pragma unroll
            for (int j = 0; j < 4; j++) {
                int row = rbase + mt * 16 + kq * 4 + j;
                if (row < N_NODES) {
                    float v = acc[mt][t][j];
                    int col = t * 16 + lr;
                    if (t < 3) P[(size_t)row * 48 + col] = __float2bfloat16(v);
                    else       R[(size_t)row * 48 + (col - 48)] = v;
                }
            }
}

// ---------- CSR gather-reduce over bf16 P: 8 lanes per node, dword (bf16x2) loads ----------
__global__ __launch_bounds__(256) void agg_csr_b16(const int* __restrict__ off, const int* __restrict__ cnt,
                                                   const int* __restrict__ csr,
                                                   const unsigned* __restrict__ P32,  // [N][24] dwords
                                                   float* __restrict__ agg) {
    int t = blockIdx.x * blockDim.x + threadIdx.x;
    int node = t >> 3, l = t & 7;
    if (node >= N_NODES) return;
    int s = off[node], len = cnt[node];
    float a0 = 0.f, a1 = 0.f, a2 = 0.f, a3 = 0.f, a4 = 0.f, a5 = 0.f;
    int i = 0;
    for (; i + 4 <= len; i += 4) {
        int sx[4];
#pragma unroll
        for (int q = 0; q < 4; q++) sx[q] = csr[s + i + q];
        unsigned uu[4][3];
#pragma unroll
        for (int q = 0; q < 4; q++) {
            const unsigned* p = P32 + (size_t)sx[q] * 24 + l;
            uu[q][0] = p[0]; uu[q][1] = p[8]; uu[q][2] = p[16];
        }
#pragma unroll
        for (int q = 0; q < 4; q++) {
            a0 += lo16(uu[q][0]); a1 += hi16(uu[q][0]);
            a2 += lo16(uu[q][1]); a3 += hi16(uu[q][1]);
            a4 += lo16(uu[q][2]); a5 += hi16(uu[q][2]);
        }
    }
    for (; i < len; i++) {
        const unsigned* p = P32 + (size_t)csr[s + i] * 24 + l;
        unsigned u0 = p[0], u1 = p[8], u2 = p[16];
        a0 += lo16(u0); a1 += hi16(u0);
        a2 += lo16(u1); a3 += hi16(u1);
        a4 += lo16(u2); a5 += hi16(u2);
    }
    size_t base = (size_t)node * 48;
    *(float2*)&agg[base +  0 + 2 * l] = make_float2(a0, a1);
    *(float2*)&agg[base + 16 + 2 * l] = make_float2(a2, a3);
    *(float2*)&agg[base + 32 + 2 * l] = make_float2(a4, a5);
}

// ---------- mean + bias + BN(eval) + ReLU -> H1 bf16 [N][64] (pad pre-zeroed) ----------
__global__ void post1_kernel(const float* __restrict__ agg, const int* __restrict__ cnt,
                             const float* __restrict__ R,
                             const float* __restrict__ b,  const float* __restrict__ g,
                             const float* __restrict__ be, const float* __restrict__ rm,
                             const float* __restrict__ rv, __hip_bfloat16* __restrict__ h) {
    int t = blockIdx.x * blockDim.x + threadIdx.x;
    if (t >= N_NODES * 48) return;
    int n = t / 48, j = t % 48;
    float mean = agg[t] / fmaxf((float)cnt[n], 1.0f);
    float v = mean + b[j] + R[t];
    v = (v - rm[j]) * (g[j] * rsqrtf(rv[j] + BN_EPS)) + be[j];
    h[(size_t)n * 64 + j] = __float2bfloat16(fmaxf(v, 0.0f));
}

// ---------- layer-2 epilogue fused with 48->4 output matvec ----------
__global__ void out_kernel(const float* __restrict__ agg, const int* __restrict__ cnt,
                           const float* __restrict__ R,
                           const float* __restrict__ b2, const float* __restrict__ g2,
                           const float* __restrict__ be2, const float* __restrict__ rm2,
                           const float* __restrict__ rv2,
                           const float* __restrict__ wo, const float* __restrict__ bo,
                           float* __restrict__ out) {
    int t = blockIdx.x * blockDim.x + threadIdx.x;
    int node = t >> 4, l = t & 15;
    if (node >= N_NODES) return;
    float dg = fmaxf((float)cnt[node], 1.0f);
    float p0 = 0.f, p1 = 0.f, p2 = 0.f, p3 = 0.f;
#pragma unroll
    for (int q = 0; q < 3; q++) {
        int j = l + q * 16;
        float v = agg[(size_t)node * 48 + j] / dg + b2[j] + R[(size_t)node * 48 + j];
        v = (v - rm2[j]) * (g2[j] * rsqrtf(rv2[j] + BN_EPS)) + be2[j];
        v = fmaxf(v, 0.f);
        p0 = fmaf(v, wo[0 * 48 + j], p0);
        p1 = fmaf(v, wo[1 * 48 + j], p1);
        p2 = fmaf(v, wo[2 * 48 + j], p2);
        p3 = fmaf(v, wo[3 * 48 + j], p3);
    }
#pragma unroll
    for (int offm = 8; offm; offm >>= 1) {
        p0 += __shfl_down(p0, offm, 16);
        p1 += __shfl_down(p1, offm, 16);
        p2 += __shfl_down(p2, offm, 16);
        p3 += __shfl_down(p3, offm, 16);
    }
    if (l == 0) {
        float4 o = make_float4(p0 + bo[0], p1 + bo[1], p2 + bo[2], p3 + bo[3]);
        *(float4*)&out[(size_t)node * 4] = o;
    }
}

extern "C" void kernel_launch(void* const* d_in, const int* in_sizes, int n_in,
                              void* d_out, int out_size, void* d_ws, size_t ws_size,
                              hipStream_t stream) {
    const float* x   = (const float*)d_in[0];
    const int*   ei  = (const int*)d_in[1];
    const float* w1l = (const float*)d_in[2];
    const float* b1  = (const float*)d_in[3];
    const float* w1r = (const float*)d_in[4];
    const float* g1  = (const float*)d_in[5];
    const float* be1 = (const float*)d_in[6];
    const float* rm1 = (const float*)d_in[7];
    const float* rv1 = (const float*)d_in[8];
    const float* w2l = (const float*)d_in[9];
    const float* b2  = (const float*)d_in[10];
    const float* w2r = (const float*)d_in[11];
    const float* g2  = (const float*)d_in[12];
    const float* be2 = (const float*)d_in[13];
    const float* rm2 = (const float*)d_in[14];
    const float* rv2 = (const float*)d_in[15];
    const float* wo  = (const float*)d_in[16];
    const float* bo  = (const float*)d_in[17];
    float* out = (float*)d_out;

    // workspace layout (all 16B-aligned)
    char* w = (char*)d_ws;
    float*           Rbuf = (float*)w;                       w += (size_t)N_NODES * 48 * 4;  // 19.2 MB
    float*           AGG  = (float*)w;                       w += (size_t)N_NODES * 48 * 4;  // 19.2 MB
    __hip_bfloat16*  P    = (__hip_bfloat16*)w;              w += (size_t)N_NODES * 48 * 2;  //  9.6 MB
    __hip_bfloat16*  H1   = (__hip_bfloat16*)w;              w += (size_t)N_NODES * 64 * 2;  // 12.8 MB
    int*             CNT  = (int*)w;                         w += (size_t)N_NODES * 4;
    int*             OFF  = (int*)w;                         w += (size_t)N_NODES * 4;
    int*             CUR  = (int*)w;                         w += (size_t)N_NODES * 4;
    int*             BSUM = (int*)w;                         w += 128 * 4;
    int*             BEX  = (int*)w;                         w += 128 * 4;
    int*             CSR  = (int*)w;                         // E * 4 = 6.4 MB
    // total ≈ 68.3 MB

    (void)hipMemsetAsync(CNT, 0, N_NODES * sizeof(int), stream);
    (void)hipMemsetAsync(H1, 0, (size_t)N_NODES * 64 * 2, stream);   // zero K-pad

    // CSR build (shared by both layers), XCD-partitioned + 8-edge ILP
    hist_part<<<NPART * NGRP, 256, 0, stream>>>(ei, CNT);
    scan_k1<<<SCAN_NB, 256, 0, stream>>>(CNT, BSUM);
    scan_k2<<<1, 128, 0, stream>>>(BSUM, BEX, SCAN_NB);
    scan_k3<<<SCAN_NB, 256, 0, stream>>>(CNT, BEX, OFF, CUR);
    scatter_part<<<NPART * NGRP, 256, 0, stream>>>(ei, CUR, CSR);

    // layer 1
    gemm1_mfma<<<(N_NODES + 127) / 128, 256, 0, stream>>>(x, w1l, w1r, P, Rbuf);
    agg_csr_b16<<<(N_NODES * 8 + 255) / 256, 256, 0, stream>>>(OFF, CNT, CSR, (const unsigned*)P, AGG);
    post1_kernel<<<(N_NODES * 48 + 255) / 256, 256, 0, stream>>>(AGG, CNT, Rbuf,
                                                                 b1, g1, be1, rm1, rv1, H1);

    // layer 2
    gemm2_mfma<<<(N_NODES + 127) / 128, 256, 0, stream>>>(H1, w2l, w2r, P, Rbuf);
    agg_csr_b16<<<(N_NODES * 8 + 255) / 256, 256, 0, stream>>>(OFF, CNT, CSR, (const unsigned*)P, AGG);
    out_kernel<<<(N_NODES * 16 + 255) / 256, 256, 0, stream>>>(AGG, CNT, Rbuf,
                                                               b2, g2, be2, rm2, rv2,
                                                               wo, bo, out);
}

// Round 8
// 457.302 us; speedup vs baseline: 2.0203x; 1.0421x over previous
//
#include <hip/hip_runtime.h>
#include <hip/hip_bf16.h>

#define N_NODES 100000
#define N_EDGES 1600000
#define IN_CH   256
#define BN_EPS  1e-5f
#define SCAN_NB 98
#define NPART   8
#define PART_SZ 12500           // N_NODES / NPART exactly
#define NGRP    800             // groups per partition; NGRP*256*8 = 1.6384M >= E

typedef __attribute__((ext_vector_type(8))) short bf16x8;
typedef __attribute__((ext_vector_type(4))) float f32x4;
typedef __attribute__((ext_vector_type(4))) int   i32x4;

// f32 -> bf16 round-to-nearest-even, on raw bits
__device__ inline unsigned f2bf(float x) {
    unsigned u = __float_as_uint(x);
    return (u + 0x7fffu + ((u >> 16) & 1u)) >> 16;
}
__device__ inline unsigned pk2(float x, float y) {
    return f2bf(x) | (f2bf(y) << 16);
}
__device__ inline bf16x8 pack8(float4 a, float4 b) {
    i32x4 r;
    r.x = (int)pk2(a.x, a.y); r.y = (int)pk2(a.z, a.w);
    r.z = (int)pk2(b.x, b.y); r.w = (int)pk2(b.z, b.w);
    return __builtin_bit_cast(bf16x8, r);
}
__device__ inline float lo16(unsigned u) { return __uint_as_float(u << 16); }
__device__ inline float hi16(unsigned u) { return __uint_as_float(u & 0xffff0000u); }

// ---------- CSR build, XCD-partitioned + 8-edge ILP (plain loads; nt hurt L3 reuse) ----------
__global__ __launch_bounds__(256) void hist_part(const int* __restrict__ ei, int* __restrict__ cnt) {
    int p = blockIdx.x & (NPART - 1);
    int g = blockIdx.x >> 3;
    int lo = p * PART_SZ, hi = lo + PART_SZ;
    int e0 = (g * 256 + (int)threadIdx.x) * 8;
    if (e0 >= N_EDGES) return;
    const i32x4* dp = (const i32x4*)(ei + N_EDGES + e0);
    i32x4 d0 = dp[0];
    i32x4 d1 = dp[1];
    int d[8] = {d0.x, d0.y, d0.z, d0.w, d1.x, d1.y, d1.z, d1.w};
#pragma unroll
    for (int j = 0; j < 8; j++)
        if (d[j] >= lo && d[j] < hi) atomicAdd(&cnt[d[j]], 1);
}

__global__ __launch_bounds__(256) void scatter_part(const int* __restrict__ ei, int* __restrict__ cur,
                                                    int* __restrict__ csr) {
    int p = blockIdx.x & (NPART - 1);
    int g = blockIdx.x >> 3;
    int lo = p * PART_SZ, hi = lo + PART_SZ;
    int e0 = (g * 256 + (int)threadIdx.x) * 8;
    if (e0 >= N_EDGES) return;
    const i32x4* dp = (const i32x4*)(ei + N_EDGES + e0);
    const i32x4* sp = (const i32x4*)(ei + e0);
    i32x4 d0 = dp[0];
    i32x4 d1 = dp[1];
    i32x4 s0 = sp[0];
    i32x4 s1 = sp[1];
    int d[8] = {d0.x, d0.y, d0.z, d0.w, d1.x, d1.y, d1.z, d1.w};
    int s[8] = {s0.x, s0.y, s0.z, s0.w, s1.x, s1.y, s1.z, s1.w};
#pragma unroll
    for (int j = 0; j < 8; j++) {
        if (d[j] >= lo && d[j] < hi && (unsigned)s[j] < N_NODES) {
            int pos = atomicAdd(&cur[d[j]], 1);
            csr[pos] = s[j];
        }
    }
}

__global__ __launch_bounds__(256) void scan_k1(const int* __restrict__ cnt, int* __restrict__ bsum) {
    __shared__ int lds[256];
    int b = blockIdx.x, t = threadIdx.x;
    int i0 = b * 1024 + t * 4;
    int s = 0;
#pragma unroll
    for (int j = 0; j < 4; j++) { int i = i0 + j; if (i < N_NODES) s += cnt[i]; }
    lds[t] = s; __syncthreads();
    for (int o = 128; o; o >>= 1) { if (t < o) lds[t] += lds[t + o]; __syncthreads(); }
    if (t == 0) bsum[b] = lds[0];
}

__global__ void scan_k2(const int* __restrict__ bsum, int* __restrict__ bex, int nb) {
    __shared__ int lds[128];
    int t = threadIdx.x;
    int v = (t < nb) ? bsum[t] : 0;
    lds[t] = v; __syncthreads();
    for (int o = 1; o < 128; o <<= 1) {
        int u = (t >= o) ? lds[t - o] : 0;
        __syncthreads();
        lds[t] += u;
        __syncthreads();
    }
    if (t < nb) bex[t] = lds[t] - v;
}

__global__ __launch_bounds__(256) void scan_k3(const int* __restrict__ cnt, const int* __restrict__ bex,
                                               int* __restrict__ off, int* __restrict__ cur) {
    __shared__ int lds[256];
    int b = blockIdx.x, t = threadIdx.x;
    int i0 = b * 1024 + t * 4;
    int c[4]; int s = 0;
#pragma unroll
    for (int j = 0; j < 4; j++) { int i = i0 + j; c[j] = (i < N_NODES) ? cnt[i] : 0; s += c[j]; }
    lds[t] = s; __syncthreads();
    for (int o = 1; o < 256; o <<= 1) {
        int u = (t >= o) ? lds[t - o] : 0;
        __syncthreads();
        lds[t] += u;
        __syncthreads();
    }
    int ex = lds[t] - s + bex[b];
#pragma unroll
    for (int j = 0; j < 4; j++) {
        int i = i0 + j;
        if (i < N_NODES) { off[i] = ex; cur[i] = ex; ex += c[j]; }
    }
}

// ---------- W fragment pre-pack: one thread per (kstep,tile,lane) fragment ----------
// Fragment for MFMA B-operand: col c = tile*16 + (lane&15), k = kstep*32 + (lane>>4)*8 + j.
__global__ void wpack(const float* __restrict__ W0, const float* __restrict__ W1,
                      int K, int nfrag, i32x4* __restrict__ WF) {
    int s = blockIdx.x * blockDim.x + threadIdx.x;
    if (s >= nfrag) return;
    int lane = s & 63, tile = (s >> 6) % 6, kstep = s / 384;
    int c = tile * 16 + (lane & 15);
    int k0 = kstep * 32 + (lane >> 4) * 8;
    const float* Wp = (c < 48) ? &W0[(size_t)c * K] : &W1[(size_t)(c - 48) * K];
    float v[8];
#pragma unroll
    for (int j = 0; j < 8; j++) { int k = k0 + j; v[j] = (k < K) ? Wp[k] : 0.f; }
    WF[s] = __builtin_bit_cast(i32x4, pack8(make_float4(v[0], v[1], v[2], v[3]),
                                            make_float4(v[4], v[5], v[6], v[7])));
}

// ---------- MFMA GEMM, layer 1: LDS-free, register B-fragments, 1-deep A prefetch ----------
// in f32 [M][256] -> P bf16 [M][48], R f32 [M][48]. 4 waves/block, 32 rows/wave.
__global__ __launch_bounds__(256) void gemm1_mfma(const float* __restrict__ in,
        const i32x4* __restrict__ WF,
        __hip_bfloat16* __restrict__ P, float* __restrict__ R) {
    int tid = threadIdx.x;
    int w = tid >> 6, lane = tid & 63;
    int lr = lane & 15, kq = lane >> 4;
    int rbase = blockIdx.x * 128 + w * 32;
    int r0 = rbase + lr, r1 = rbase + 16 + lr;
    const float* ap0 = in + (size_t)(r0 < N_NODES ? r0 : N_NODES - 1) * IN_CH;
    const float* ap1 = in + (size_t)(r1 < N_NODES ? r1 : N_NODES - 1) * IN_CH;

    f32x4 acc[2][6] = {};
    float4 c0a = *(const float4*)(ap0 + kq * 8);
    float4 c0b = *(const float4*)(ap0 + kq * 8 + 4);
    float4 c1a = *(const float4*)(ap1 + kq * 8);
    float4 c1b = *(const float4*)(ap1 + kq * 8 + 4);

    for (int kstep = 0; kstep < 8; kstep++) {
        i32x4 bf[6];
#pragma unroll
        for (int t = 0; t < 6; t++) bf[t] = WF[(kstep * 6 + t) * 64 + lane];
        float4 n0a, n0b, n1a, n1b;
        if (kstep < 7) {
            int kb = (kstep + 1) * 32 + kq * 8;
            n0a = *(const float4*)(ap0 + kb); n0b = *(const float4*)(ap0 + kb + 4);
            n1a = *(const float4*)(ap1 + kb); n1b = *(const float4*)(ap1 + kb + 4);
        }
        bf16x8 af0 = pack8(c0a, c0b);
        bf16x8 af1 = pack8(c1a, c1b);
#pragma unroll
        for (int t = 0; t < 6; t++) {
            bf16x8 bfr = __builtin_bit_cast(bf16x8, bf[t]);
            acc[0][t] = __builtin_amdgcn_mfma_f32_16x16x32_bf16(af0, bfr, acc[0][t], 0, 0, 0);
            acc[1][t] = __builtin_amdgcn_mfma_f32_16x16x32_bf16(af1, bfr, acc[1][t], 0, 0, 0);
        }
        if (kstep < 7) { c0a = n0a; c0b = n0b; c1a = n1a; c1b = n1b; }
    }
#pragma unroll
    for (int mt = 0; mt < 2; mt++)
#pragma unroll
        for (int t = 0; t < 6; t++)
#pragma unroll
            for (int j = 0; j < 4; j++) {
                int row = rbase + mt * 16 + kq * 4 + j;
                if (row < N_NODES) {
                    float v = acc[mt][t][j];
                    int col = t * 16 + lr;
                    if (t < 3) P[(size_t)row * 48 + col] = __float2bfloat16(v);
                    else       R[(size_t)row * 48 + (col - 48)] = v;
                }
            }
}

// ---------- MFMA GEMM, layer 2: LDS-free; in bf16 [M][64] (zero-padded K) ----------
__global__ __launch_bounds__(256) void gemm2_mfma(const __hip_bfloat16* __restrict__ inb,
        const i32x4* __restrict__ WF,
        __hip_bfloat16* __restrict__ P, float* __restrict__ R) {
    int tid = threadIdx.x;
    int w = tid >> 6, lane = tid & 63;
    int lr = lane & 15, kq = lane >> 4;
    int rbase = blockIdx.x * 128 + w * 32;
    int r0 = rbase + lr, r1 = rbase + 16 + lr;
    const __hip_bfloat16* ap0 = inb + (size_t)(r0 < N_NODES ? r0 : N_NODES - 1) * 64;
    const __hip_bfloat16* ap1 = inb + (size_t)(r1 < N_NODES ? r1 : N_NODES - 1) * 64;

    f32x4 acc[2][6] = {};
#pragma unroll
    for (int kstep = 0; kstep < 2; kstep++) {
        int kb = kstep * 32 + kq * 8;
        bf16x8 af0 = *(const bf16x8*)(ap0 + kb);
        bf16x8 af1 = *(const bf16x8*)(ap1 + kb);
        i32x4 bf[6];
#pragma unroll
        for (int t = 0; t < 6; t++) bf[t] = WF[(kstep * 6 + t) * 64 + lane];
#pragma unroll
        for (int t = 0; t < 6; t++) {
            bf16x8 bfr = __builtin_bit_cast(bf16x8, bf[t]);
            acc[0][t] = __builtin_amdgcn_mfma_f32_16x16x32_bf16(af0, bfr, acc[0][t], 0, 0, 0);
            acc[1][t] = __builtin_amdgcn_mfma_f32_16x16x32_bf16(af1, bfr, acc[1][t], 0, 0, 0);
        }
    }
#pragma unroll
    for (int mt = 0; mt < 2; mt++)
#pragma unroll
        for (int t = 0; t < 6; t++)
#pragma unroll
            for (int j = 0; j < 4; j++) {
                int row = rbase + mt * 16 + kq * 4 + j;
                if (row < N_NODES) {
                    float v = acc[mt][t][j];
                    int col = t * 16 + lr;
                    if (t < 3) P[(size_t)row * 48 + col] = __float2bfloat16(v);
                    else       R[(size_t)row * 48 + (col - 48)] = v;
                }
            }
}

// ---------- CSR gather-reduce over bf16 P: 8 lanes per node, dword (bf16x2) loads ----------
__global__ __launch_bounds__(256) void agg_csr_b16(const int* __restrict__ off, const int* __restrict__ cnt,
                                                   const int* __restrict__ csr,
                                                   const unsigned* __restrict__ P32,  // [N][24] dwords
                                                   float* __restrict__ agg) {
    int t = blockIdx.x * blockDim.x + threadIdx.x;
    int node = t >> 3, l = t & 7;
    if (node >= N_NODES) return;
    int s = off[node], len = cnt[node];
    float a0 = 0.f, a1 = 0.f, a2 = 0.f, a3 = 0.f, a4 = 0.f, a5 = 0.f;
    int i = 0;
    for (; i + 4 <= len; i += 4) {
        int sx[4];
#pragma unroll
        for (int q = 0; q < 4; q++) sx[q] = csr[s + i + q];
        unsigned uu[4][3];
#pragma unroll
        for (int q = 0; q < 4; q++) {
            const unsigned* p = P32 + (size_t)sx[q] * 24 + l;
            uu[q][0] = p[0]; uu[q][1] = p[8]; uu[q][2] = p[16];
        }
#pragma unroll
        for (int q = 0; q < 4; q++) {
            a0 += lo16(uu[q][0]); a1 += hi16(uu[q][0]);
            a2 += lo16(uu[q][1]); a3 += hi16(uu[q][1]);
            a4 += lo16(uu[q][2]); a5 += hi16(uu[q][2]);
        }
    }
    for (; i < len; i++) {
        const unsigned* p = P32 + (size_t)csr[s + i] * 24 + l;
        unsigned u0 = p[0], u1 = p[8], u2 = p[16];
        a0 += lo16(u0); a1 += hi16(u0);
        a2 += lo16(u1); a3 += hi16(u1);
        a4 += lo16(u2); a5 += hi16(u2);
    }
    size_t base = (size_t)node * 48;
    *(float2*)&agg[base +  0 + 2 * l] = make_float2(a0, a1);
    *(float2*)&agg[base + 16 + 2 * l] = make_float2(a2, a3);
    *(float2*)&agg[base + 32 + 2 * l] = make_float2(a4, a5);
}

// ---------- mean + bias + BN(eval) + ReLU -> H1 bf16 [N][64] (pad pre-zeroed) ----------
__global__ void post1_kernel(const float* __restrict__ agg, const int* __restrict__ cnt,
                             const float* __restrict__ R,
                             const float* __restrict__ b,  const float* __restrict__ g,
                             const float* __restrict__ be, const float* __restrict__ rm,
                             const float* __restrict__ rv, __hip_bfloat16* __restrict__ h) {
    int t = blockIdx.x * blockDim.x + threadIdx.x;
    if (t >= N_NODES * 48) return;
    int n = t / 48, j = t % 48;
    float mean = agg[t] / fmaxf((float)cnt[n], 1.0f);
    float v = mean + b[j] + R[t];
    v = (v - rm[j]) * (g[j] * rsqrtf(rv[j] + BN_EPS)) + be[j];
    h[(size_t)n * 64 + j] = __float2bfloat16(fmaxf(v, 0.0f));
}

// ---------- layer-2 epilogue fused with 48->4 output matvec ----------
__global__ void out_kernel(const float* __restrict__ agg, const int* __restrict__ cnt,
                           const float* __restrict__ R,
                           const float* __restrict__ b2, const float* __restrict__ g2,
                           const float* __restrict__ be2, const float* __restrict__ rm2,
                           const float* __restrict__ rv2,
                           const float* __restrict__ wo, const float* __restrict__ bo,
                           float* __restrict__ out) {
    int t = blockIdx.x * blockDim.x + threadIdx.x;
    int node = t >> 4, l = t & 15;
    if (node >= N_NODES) return;
    float dg = fmaxf((float)cnt[node], 1.0f);
    float p0 = 0.f, p1 = 0.f, p2 = 0.f, p3 = 0.f;
#pragma unroll
    for (int q = 0; q < 3; q++) {
        int j = l + q * 16;
        float v = agg[(size_t)node * 48 + j] / dg + b2[j] + R[(size_t)node * 48 + j];
        v = (v - rm2[j]) * (g2[j] * rsqrtf(rv2[j] + BN_EPS)) + be2[j];
        v = fmaxf(v, 0.f);
        p0 = fmaf(v, wo[0 * 48 + j], p0);
        p1 = fmaf(v, wo[1 * 48 + j], p1);
        p2 = fmaf(v, wo[2 * 48 + j], p2);
        p3 = fmaf(v, wo[3 * 48 + j], p3);
    }
#pragma unroll
    for (int offm = 8; offm; offm >>= 1) {
        p0 += __shfl_down(p0, offm, 16);
        p1 += __shfl_down(p1, offm, 16);
        p2 += __shfl_down(p2, offm, 16);
        p3 += __shfl_down(p3, offm, 16);
    }
    if (l == 0) {
        float4 o = make_float4(p0 + bo[0], p1 + bo[1], p2 + bo[2], p3 + bo[3]);
        *(float4*)&out[(size_t)node * 4] = o;
    }
}

extern "C" void kernel_launch(void* const* d_in, const int* in_sizes, int n_in,
                              void* d_out, int out_size, void* d_ws, size_t ws_size,
                              hipStream_t stream) {
    const float* x   = (const float*)d_in[0];
    const int*   ei  = (const int*)d_in[1];
    const float* w1l = (const float*)d_in[2];
    const float* b1  = (const float*)d_in[3];
    const float* w1r = (const float*)d_in[4];
    const float* g1  = (const float*)d_in[5];
    const float* be1 = (const float*)d_in[6];
    const float* rm1 = (const float*)d_in[7];
    const float* rv1 = (const float*)d_in[8];
    const float* w2l = (const float*)d_in[9];
    const float* b2  = (const float*)d_in[10];
    const float* w2r = (const float*)d_in[11];
    const float* g2  = (const float*)d_in[12];
    const float* be2 = (const float*)d_in[13];
    const float* rm2 = (const float*)d_in[14];
    const float* rv2 = (const float*)d_in[15];
    const float* wo  = (const float*)d_in[16];
    const float* bo  = (const float*)d_in[17];
    float* out = (float*)d_out;

    // workspace layout (all 16B-aligned)
    char* w = (char*)d_ws;
    float*           Rbuf = (float*)w;                       w += (size_t)N_NODES * 48 * 4;  // 19.2 MB
    float*           AGG  = (float*)w;                       w += (size_t)N_NODES * 48 * 4;  // 19.2 MB
    __hip_bfloat16*  P    = (__hip_bfloat16*)w;              w += (size_t)N_NODES * 48 * 2;  //  9.6 MB
    __hip_bfloat16*  H1   = (__hip_bfloat16*)w;              w += (size_t)N_NODES * 64 * 2;  // 12.8 MB
    int*             CNT  = (int*)w;                         w += (size_t)N_NODES * 4;
    int*             OFF  = (int*)w;                         w += (size_t)N_NODES * 4;
    int*             CUR  = (int*)w;                         w += (size_t)N_NODES * 4;
    int*             BSUM = (int*)w;                         w += 128 * 4;
    int*             BEX  = (int*)w;                         w += 128 * 4;
    i32x4*           WF1  = (i32x4*)w;                       w += 3072 * 16;                 // 48 KB
    i32x4*           WF2  = (i32x4*)w;                       w += 768 * 16;                  // 12 KB
    int*             CSR  = (int*)w;                         // E * 4 = 6.4 MB
    // total ≈ 68.4 MB

    (void)hipMemsetAsync(CNT, 0, N_NODES * sizeof(int), stream);
    (void)hipMemsetAsync(H1, 0, (size_t)N_NODES * 64 * 2, stream);   // zero K-pad

    // W fragment pre-pack (tiny; L2-resident afterwards)
    wpack<<<12, 256, 0, stream>>>(w1l, w1r, IN_CH, 3072, WF1);
    wpack<<<3, 256, 0, stream>>>(w2l, w2r, 48, 768, WF2);

    // CSR build (shared by both layers), XCD-partitioned + 8-edge ILP
    hist_part<<<NPART * NGRP, 256, 0, stream>>>(ei, CNT);
    scan_k1<<<SCAN_NB, 256, 0, stream>>>(CNT, BSUM);
    scan_k2<<<1, 128, 0, stream>>>(BSUM, BEX, SCAN_NB);
    scan_k3<<<SCAN_NB, 256, 0, stream>>>(CNT, BEX, OFF, CUR);
    scatter_part<<<NPART * NGRP, 256, 0, stream>>>(ei, CUR, CSR);

    // layer 1
    gemm1_mfma<<<(N_NODES + 127) / 128, 256, 0, stream>>>(x, WF1, P, Rbuf);
    agg_csr_b16<<<(N_NODES * 8 + 255) / 256, 256, 0, stream>>>(OFF, CNT, CSR, (const unsigned*)P, AGG);
    post1_kernel<<<(N_NODES * 48 + 255) / 256, 256, 0, stream>>>(AGG, CNT, Rbuf,
                                                                 b1, g1, be1, rm1, rv1, H1);

    // layer 2
    gemm2_mfma<<<(N_NODES + 127) / 128, 256, 0, stream>>>(H1, WF2, P, Rbuf);
    agg_csr_b16<<<(N_NODES * 8 + 255) / 256, 256, 0, stream>>>(OFF, CNT, CSR, (const unsigned*)P, AGG);
    out_kernel<<<(N_NODES * 16 + 255) / 256, 256, 0, stream>>>(AGG, CNT, Rbuf,
                                                               b2, g2, be2, rm2, rv2,
                                                               wo, bo, out);
}